// Round 10
// baseline (273.538 us; speedup 1.0000x reference)
//
#include <hip/hip_runtime.h>
#include <hip/hip_bf16.h>

typedef __hip_bfloat16 bf16;
typedef unsigned short u16;
typedef __attribute__((ext_vector_type(8))) short s8v;     // 8 bf16 (4 VGPRs) MFMA frag
typedef __attribute__((ext_vector_type(4))) float f32x4;   // 16x16 acc frag
typedef __attribute__((ext_vector_type(16))) float f32x16; // 32x32 acc frag

#define NP    2048
#define DC    256
#define MA    128
#define KNN_  16
#define LKV   768   // merged K|Q|V row stride

#define MFMA_B16(a,b,c) __builtin_amdgcn_mfma_f32_16x16x32_bf16(a,b,c,0,0,0)
#define MFMA32(a,b,c)   __builtin_amdgcn_mfma_f32_32x32x16_bf16(a,b,c,0,0,0)

__device__ __forceinline__ float u2f(u16 u){ return __uint_as_float(((unsigned int)u)<<16); }
__device__ __forceinline__ u16 f2u(float f){ bf16 h=__float2bfloat16(f); u16 us; __builtin_memcpy(&us,&h,2); return us; }

// packed A-frag load: layout [((rb*KS+ks)*64+l)*8 + j]
__device__ __forceinline__ s8v ldpk(const u16* pk, int rb, int KS, int ks, int l){
  return *(const s8v*)(pk + (((size_t)((rb*KS + ks)*64 + l))<<3));
}
// LDS B-frag read, 16B, XOR-swizzled. rshift = log2(row bytes)
__device__ __forceinline__ s8v ldsB(const u16* base, int col, int k0, int rshift){
  int byte = ((col<<rshift) + (k0<<1)) ^ ((col&7)<<4);
  return *(const s8v*)((const char*)base + byte);
}
// LDS 4x bf16 write (8B), swizzled
__device__ __forceinline__ void st2(u16* base, int col, int ch0, int rshift,
                                    float v0, float v1, float v2, float v3){
  uint2 pkv;
  pkv.x = (unsigned)f2u(v0) | ((unsigned)f2u(v1)<<16);
  pkv.y = (unsigned)f2u(v2) | ((unsigned)f2u(v3)<<16);
  int byte = ((col<<rshift) + (ch0<<1)) ^ ((col&7)<<4);
  *(uint2*)((char*)base + byte) = pkv;
}
// LDS single bf16 write, swizzled
__device__ __forceinline__ void st1(u16* base, int col, int ch, int rshift, float v){
  int byte = ((col<<rshift) + (ch<<1)) ^ ((col&7)<<4);
  *(u16*)((char*)base + byte) = f2u(v);
}
// LDS 4x bf16 read (8B), swizzled
__device__ __forceinline__ void ld4s(const u16* base, int col, int ch0, int rshift, float* o){
  int byte = ((col<<rshift) + (ch0<<1)) ^ ((col&7)<<4);
  uint2 pkv = *(const uint2*)((const char*)base + byte);
  o[0] = u2f(pkv.x & 0xffff); o[1] = u2f(pkv.x>>16);
  o[2] = u2f(pkv.y & 0xffff); o[3] = u2f(pkv.y>>16);
}

// ---------------- MFMA GEMM (16x16 path, unchanged) ----------------
template<bool XT, bool OT, bool RES>
__global__ __launch_bounds__(256) void mgemm(
    const u16* __restrict__ apk, const float* __restrict__ X,
    const float* __restrict__ bias, const float* __restrict__ resid,
    float* __restrict__ out, int M, int N, int K, int ldo)
{
  __shared__ u16 Bt[64*256];
  const int tid = threadIdx.x;
  const int w = tid>>6, l = tid&63, k = l&15, g = l>>4;
  const int n0 = blockIdx.x*64, m0 = blockIdx.y*128, bb = blockIdx.z;
  const int KS = K >> 5;
  if constexpr (!XT) {
    for (int e = tid*4; e < 64*K; e += 1024) {
      int kk = e >> 6, c = e & 63;
      float4 v = *(const float4*)(X + (size_t)bb*K*N + (size_t)kk*N + n0 + c);
      st1(Bt, c+0, kk, 9, v.x); st1(Bt, c+1, kk, 9, v.y);
      st1(Bt, c+2, kk, 9, v.z); st1(Bt, c+3, kk, 9, v.w);
    }
  } else {
    for (int e = tid*4; e < 64*256; e += 1024) {
      int c = e >> 8, kk = e & 255;
      float4 v = *(const float4*)(X + ((size_t)bb*N + n0 + c)*256 + kk);
      st2(Bt, c, kk, 9, v.x, v.y, v.z, v.w);
    }
  }
  __syncthreads();
  f32x4 acc[2][4] = {};
  const int rbase = (m0>>4) + w*2;
  for (int ks = 0; ks < KS; ks++) {
    s8v a0 = ldpk(apk, rbase,   KS, ks, l);
    s8v a1 = ldpk(apk, rbase+1, KS, ks, l);
#pragma unroll
    for (int cf = 0; cf < 4; cf++) {
      s8v bF = ldsB(Bt, cf*16 + k, ks*32 + g*8, 9);
      acc[0][cf] = MFMA_B16(a0, bF, acc[0][cf]);
      acc[1][cf] = MFMA_B16(a1, bF, acc[1][cf]);
    }
  }
#pragma unroll
  for (int ri = 0; ri < 2; ri++) {
    int mrow = m0 + w*32 + ri*16 + g*4;
#pragma unroll
    for (int r = 0; r < 4; r++) {
      int m = mrow + r;
      float bv = bias[m];
#pragma unroll
      for (int cf = 0; cf < 4; cf++) {
        int n = n0 + cf*16 + k;
        float v = acc[ri][cf][r] + bv;
        if constexpr (RES) v += resid[((size_t)bb*M + m)*N + n];
        if constexpr (OT) out[((size_t)bb*N + n)*ldo + m] = v;
        else              out[((size_t)bb*M + m)*N + n] = v;
      }
    }
  }
}

// ---------------- KNN top-16 (unchanged) ----------------
__global__ __launch_bounds__(1024) void knn_kernel(const float* __restrict__ pos, int* __restrict__ idx)
{
  __shared__ float px[NP], py[NP], pz[NP], pn[NP];
  const int tid = threadIdx.x;
  const int w = tid >> 6, l = tid & 63;
  const int bb = blockIdx.x >> 7;
  const int q0 = (blockIdx.x & 127) * 16;
  const float* pp = pos + (size_t)bb * 3 * NP;
  for (int t = tid; t < NP; t += 1024) {
    float x = pp[t], y = pp[NP + t], z = pp[2*NP + t];
    px[t] = x; py[t] = y; pz[t] = z; pn[t] = x*x + y*y + z*z;
  }
  __syncthreads();
  const int qi = q0 + w;
  const float qx = px[qi], qy = py[qi], qz = pz[qi], qn = pn[qi];
  float bd[16]; int bi[16];
#pragma unroll
  for (int t = 0; t < 16; t++) { bd[t] = 3.4e38f; bi[t] = -1; }
  float worst = 3.4e38f;
  for (int t = 0; t < 32; t++) {
    int j = t*64 + l;
    float d = qn + pn[j] - 2.f * (qx*px[j] + qy*py[j] + qz*pz[j]);
    if (__any(d < worst)) {
      float cd = (d < worst) ? d : 3.4e38f;
      int   cj = j;
#pragma unroll
      for (int s = 0; s < 16; s++) {
        bool sw = cd < bd[s];
        float od = bd[s]; int oj = bi[s];
        bd[s] = sw ? cd : od;  bi[s] = sw ? cj : oj;
        cd    = sw ? od : cd;  cj    = sw ? oj : cj;
      }
      worst = bd[15];
    }
  }
  int myj = 0;
#pragma unroll
  for (int r = 0; r < 16; r++) {
    float md = bd[0]; int mj = bi[0];
#pragma unroll
    for (int o = 1; o < 64; o <<= 1) {
      float od = __shfl_xor(md, o);
      int   oj = __shfl_xor(mj, o);
      bool tk = (od < md) || (od == md && ((unsigned)oj < (unsigned)mj));
      md = tk ? od : md;  mj = tk ? oj : mj;
    }
    if (l == r) myj = mj;
    bool win = (bi[0] == mj);
#pragma unroll
    for (int s = 0; s < 15; s++) {
      bd[s] = win ? bd[s+1] : bd[s];
      bi[s] = win ? bi[s+1] : bi[s];
    }
    bd[15] = win ? 3.4e38f : bd[15];
  }
  if (l < 16) idx[((size_t)bb * NP + qi) * KNN_ + l] = myj;
}

// ---------------- prep: aw1/aw2/W' packed for 32x32x16; mgemm weights 16x16 ---------
__global__ __launch_bounds__(256) void prep_kernel(
    const float* __restrict__ aw1, const float* __restrict__ aw2,
    const float* __restrict__ lw3, const float* __restrict__ pw2,
    const float* __restrict__ w_start, const float* __restrict__ w_key,
    const float* __restrict__ w_query, const float* __restrict__ w_value,
    const float* __restrict__ w_end,
    const float* __restrict__ b_key, const float* __restrict__ b_query,
    const float* __restrict__ b_value,
    const float* __restrict__ ag1, const float* __restrict__ ab1, const float* __restrict__ abt1,
    const float* __restrict__ pg1, const float* __restrict__ pb1, const float* __restrict__ pbt1,
    u16* __restrict__ aw1pk, u16* __restrict__ aw2pk, u16* __restrict__ wppk,
    u16* __restrict__ wstpk, u16* __restrict__ wkqvpk, u16* __restrict__ wendpk,
    float* __restrict__ sa, float* __restrict__ oa, float* __restrict__ sp,
    float* __restrict__ op_, float* __restrict__ bkqv)
{
  int i = blockIdx.x * 256 + threadIdx.x;
  const float inv = rsqrtf(1.0f + 1e-5f);
  if (i < 262144) {  // aw1 (1024x256) for 32x32: rb 0..31, KS=16
    int j = i & 7, l = (i >> 3) & 63, ks = (i >> 9) & 15, rb = i >> 13;
    int row = rb*32 + (l & 31), colk = ks*16 + (l >> 5)*8 + j;
    aw1pk[i] = f2u(aw1[(size_t)row*256 + colk]); return;
  }
  i -= 262144;
  if (i < 262144) {  // aw2 (256x1024) for 32x32: rb 0..7, KS=64
    int j = i & 7, l = (i >> 3) & 63, ks = (i >> 9) & 63, rb = i >> 15;
    int row = rb*32 + (l & 31), colk = ks*16 + (l >> 5)*8 + j;
    aw2pk[i] = f2u(aw2[(size_t)row*1024 + colk]); return;
  }
  i -= 262144;
  if (i < 32768) {   // W' = [lw3 | pw2] (256x128) for 32x32: rb 0..7, KS=8
    int j = i & 7, l = (i >> 3) & 63, ks = (i >> 9) & 7, rb = i >> 12;
    int row = rb*32 + (l & 31), colk = ks*16 + (l >> 5)*8 + j;
    float v = (colk < 64) ? lw3[row*64 + colk] : pw2[row*64 + (colk - 64)];
    wppk[i] = f2u(v); return;
  }
  i -= 32768;
  if (i < 32768) {   // w_start (256x128), 16x16 pack, KS=4
    int rb = i >> 11, rem = i & 2047, ks = rem >> 9, l = (rem >> 3) & 63, j = rem & 7;
    int row = rb*16 + (l & 15), colk = ks*32 + (l >> 4)*8 + j;
    wstpk[i] = f2u(w_start[(size_t)row*128 + colk]); return;
  }
  i -= 32768;
  if (i < 196608) {  // [w_key; w_query; w_value] (768x256), 16x16 pack, KS=8
    int rb = i >> 12, rem = i & 4095, ks = rem >> 9, l = (rem >> 3) & 63, j = rem & 7;
    int row = rb*16 + (l & 15), colk = ks*32 + (l >> 4)*8 + j;
    float v = (row < 256) ? w_key[(size_t)row*256 + colk]
            : (row < 512) ? w_query[(size_t)(row-256)*256 + colk]
                          : w_value[(size_t)(row-512)*256 + colk];
    wkqvpk[i] = f2u(v); return;
  }
  i -= 196608;
  if (i < 32768) {   // w_end (128x256), 16x16 pack, KS=8
    int rb = i >> 12, rem = i & 4095, ks = rem >> 9, l = (rem >> 3) & 63, j = rem & 7;
    int row = rb*16 + (l & 15), colk = ks*32 + (l >> 4)*8 + j;
    wendpk[i] = f2u(w_end[(size_t)row*256 + colk]); return;
  }
  i -= 32768;
  if (i < 1024) { float s_ = ag1[i]*inv; sa[i] = s_; oa[i] = ab1[i]*s_ + abt1[i]; return; }
  i -= 1024;
  if (i < 64)  { float s_ = pg1[i]*inv; sp[i] = s_; op_[i] = pb1[i]*s_ + pbt1[i]; return; }
  i -= 64;
  if (i < 768) {
    bkqv[i] = (i < 256) ? b_key[i] : (i < 512) ? b_query[i-256] : b_value[i-512];
  }
}

// ---------------- fused: 32x32x16 MFMA core ----------
// 256 threads = 4 waves, 4 points (64 cols). Wave w owns output ch [w*64,+64)
// (2 row-frags of 32) x 64 cols (2 col-frags of 32). 4 chunks of 256 hidden.
// Issue economics: 2x FLOP/instr and 2x FLOP per ds_read vs 16x16x32 (R9 showed
// occupancy is NOT the binding constraint; LDS-read issue per MFMA is).
// C/D layout (m74/m101): col=lane&31, ch=(reg&3)+8*(reg>>2)+4*(lane>>5).
__global__ __launch_bounds__(256, 2) void fused_attn(
    const float* __restrict__ kqv, const int* __restrict__ knn_idx,
    const float* __restrict__ pos, const int* __restrict__ map_idx,
    const float* __restrict__ P_anchor, const float* __restrict__ adist,
    const float* __restrict__ lw1f, const float* __restrict__ lw2f, const float* __restrict__ pw1f,
    const float* __restrict__ spv, const float* __restrict__ opv, const float* __restrict__ pb2f,
    const u16* __restrict__ aw1pk, const float* __restrict__ sav, const float* __restrict__ oav,
    const u16* __restrict__ aw2pk, const u16* __restrict__ wppk, const float* __restrict__ ab2f,
    float* __restrict__ aggT)
{
  // 64 KiB: s_t [64][256] swz rshift9 (32KB) @0; hid_t [64][256] swz rshift9 (32KB) @32768.
  // P0-P2 scratch overlays the (not-yet-written) s_t region; dead before s_t writes.
  __shared__ __align__(16) char smem[65536];
  u16*   s_t   = (u16*)smem;
  u16*   hid_t = (u16*)(smem + 32768);
  float* fFEAT = (float*)smem;               // [4][6][17] f32  (1632 B)
  float* fPREL = (float*)(smem + 1632);      // [4][3][17] f32  (816 B)
  u16*   fH1   = (u16*) (smem + 2448);       // [4][32][17] u16 (4352 B)

  const int tid = threadIdx.x;
  const int w = tid >> 6, l = tid & 63;
  const int k = l & 15, g = l >> 4;          // P0-P2 addressing
  const int c32 = l & 31, h = l >> 5;        // 32x32 MFMA addressing
  const int p0 = blockIdx.x * 4;
  const int b = p0 >> 11, pi0 = p0 & 2047;
  const int pi = pi0 + w;
  const int col_w = w*16 + k;

  const float* kqvB = kqv + (size_t)b * NP * LKV;
  const int* knnB = knn_idx + ((size_t)b * NP) * KNN_;

  // ---- P0: geometric features (16 lanes per wave; point = w) ----
  if (l < 16) {
    int kk = l;
    int j = knnB[(size_t)pi * KNN_ + kk];
    const float* pp = pos + (size_t)b * 3 * NP;
    float qx = pp[pi], qy = pp[NP+pi], qz = pp[2*NP+pi];
    float nx = pp[j],  ny = pp[NP+j],  nz = pp[2*NP+j];
    float r1x = qx-nx, r1y = qy-ny, r1z = qz-nz;
    fPREL[(w*3+0)*17+kk] = r1x; fPREL[(w*3+1)*17+kk] = r1y; fPREL[(w*3+2)*17+kk] = r1z;
    int mi = map_idx[b*NP + pi];
    int bj = map_idx[b*NP + j];
    const float* pa = P_anchor + (size_t)b * MA * 3;
    float ax = pa[mi*3], ay = pa[mi*3+1], az = pa[mi*3+2];
    float bx = pa[bj*3], by = pa[bj*3+1], bz = pa[bj*3+2];
    float dA = sqrtf((qx-ax)*(qx-ax)+(qy-ay)*(qy-ay)+(qz-az)*(qz-az));
    float dB = sqrtf((nx-bx)*(nx-bx)+(ny-by)*(ny-by)+(nz-bz)*(nz-bz));
    float dAB = adist[(size_t)b*MA*MA + mi*MA + bj];
    float r2 = dA + dAB + dB;
    fFEAT[(w*6+0)*17+kk] = fabsf(r1x); fFEAT[(w*6+1)*17+kk] = fabsf(r1y);
    fFEAT[(w*6+2)*17+kk] = fabsf(r1z);
    fFEAT[(w*6+3)*17+kk] = r2; fFEAT[(w*6+4)*17+kk] = r2; fFEAT[(w*6+5)*17+kk] = r2;
  }
  __syncthreads();

  // ---- P1: h1 = relu(lw1 @ feats) (32x16 per point) ----
  {
    float f0=fFEAT[(w*6+0)*17+k], f1=fFEAT[(w*6+1)*17+k], f2=fFEAT[(w*6+2)*17+k],
          f3=fFEAT[(w*6+3)*17+k], f4=fFEAT[(w*6+4)*17+k], f5=fFEAT[(w*6+5)*17+k];
#pragma unroll
    for (int jj = 0; jj < 8; jj++) {
      int hh = g*8 + jj;
      const float* wp = lw1f + hh*6;
      float v = wp[0]*f0 + wp[1]*f1 + wp[2]*f2 + wp[3]*f3 + wp[4]*f4 + wp[5]*f5;
      fH1[(w*32+hh)*17+k] = f2u(fmaxf(v, 0.f));
    }
  }
  __syncthreads();

  // ---- P2: h2 -> hid_t[col][0..64); ph -> hid_t[col][64..128) (rshift 9) ----
  {
    float hr[32];
#pragma unroll
    for (int t = 0; t < 32; t++) hr[t] = u2f(fH1[(w*32+t)*17+k]);
#pragma unroll
    for (int jj = 0; jj < 16; jj++) {
      int hh = g*16 + jj;
      const float4* wp = (const float4*)(lw2f + hh*32);
      float a = 0.f;
#pragma unroll
      for (int t4 = 0; t4 < 8; t4++) {
        float4 wv = wp[t4];
        a += wv.x*hr[t4*4] + wv.y*hr[t4*4+1] + wv.z*hr[t4*4+2] + wv.w*hr[t4*4+3];
      }
      st1(hid_t, col_w, hh, 9, fmaxf(a, 0.f));
    }
    float pr0 = fPREL[(w*3+0)*17+k], pr1 = fPREL[(w*3+1)*17+k], pr2 = fPREL[(w*3+2)*17+k];
#pragma unroll
    for (int jj = 0; jj < 16; jj++) {
      int hh = g*16 + jj;
      float d = pw1f[hh*3]*pr0 + pw1f[hh*3+1]*pr1 + pw1f[hh*3+2]*pr2;
      st1(hid_t, col_w, 64 + hh, 9, fmaxf(d*spv[hh] + opv[hh], 0.f));
    }
  }
  __syncthreads();

  // ---- s-build (32x32): s = (q - k_g + pb2) + W'@H (K=128) ----
  {
    f32x16 accs[2][2];
#pragma unroll
    for (int fr = 0; fr < 2; fr++)
#pragma unroll
    for (int fc = 0; fc < 2; fc++) {
      int p = fc*2 + (c32 >> 4), kk = c32 & 15;
      int j = knnB[(size_t)(pi0 + p)*KNN_ + kk];
      const float* qrow = kqvB + (size_t)(pi0 + p)*LKV + 256;
      const float* krow = kqvB + (size_t)j*LKV;
#pragma unroll
      for (int q = 0; q < 4; q++) {
        int ch0 = w*64 + fr*32 + q*8 + 4*h;
        float4 q4 = *(const float4*)(qrow + ch0);
        float4 k4 = *(const float4*)(krow + ch0);
        float4 p4 = *(const float4*)(pb2f + ch0);
        accs[fr][fc][q*4+0] = q4.x - k4.x + p4.x;
        accs[fr][fc][q*4+1] = q4.y - k4.y + p4.y;
        accs[fr][fc][q*4+2] = q4.z - k4.z + p4.z;
        accs[fr][fc][q*4+3] = q4.w - k4.w + p4.w;
      }
    }
#pragma unroll
    for (int ks = 0; ks < 8; ks++) {
      s8v a0 = ldpk(wppk, w*2 + 0, 8, ks, l);
      s8v a1 = ldpk(wppk, w*2 + 1, 8, ks, l);
#pragma unroll
      for (int fc = 0; fc < 2; fc++) {
        s8v bF = ldsB(hid_t, fc*32 + c32, ks*16 + h*8, 9);
        accs[0][fc] = MFMA32(a0, bF, accs[0][fc]);
        accs[1][fc] = MFMA32(a1, bF, accs[1][fc]);
      }
    }
#pragma unroll
    for (int fr = 0; fr < 2; fr++)
#pragma unroll
    for (int fc = 0; fc < 2; fc++)
#pragma unroll
      for (int q = 0; q < 4; q++)
        st2(s_t, fc*32 + c32, w*64 + fr*32 + q*8 + 4*h, 9,
            accs[fr][fc][q*4+0], accs[fr][fc][q*4+1],
            accs[fr][fc][q*4+2], accs[fr][fc][q*4+3]);
  }
  __syncthreads();

  // ---- attention MLP: 4 chunks of 256 hidden ----
  f32x16 acc2[2][2];
#pragma unroll
  for (int fr = 0; fr < 2; fr++)
#pragma unroll
  for (int fc = 0; fc < 2; fc++)
#pragma unroll
    for (int q = 0; q < 4; q++) {
      int ch0 = w*64 + fr*32 + q*8 + 4*h;
      float4 a4 = *(const float4*)(ab2f + ch0);
      acc2[fr][fc][q*4+0] = a4.x; acc2[fr][fc][q*4+1] = a4.y;
      acc2[fr][fc][q*4+2] = a4.z; acc2[fr][fc][q*4+3] = a4.w;
    }

  for (int c = 0; c < 4; c++) {
    // layer 1: hidden [c*256,+256) = 8 row-frags; wave w owns frags c*8+w, c*8+w+4
    f32x16 acc1[2][2] = {};
    const int rb0 = c*8 + w, rb1 = rb0 + 4;
#pragma unroll
    for (int ks = 0; ks < 16; ks++) {
      s8v a0 = ldpk(aw1pk, rb0, 16, ks, l);
      s8v a1 = ldpk(aw1pk, rb1, 16, ks, l);
#pragma unroll
      for (int fc = 0; fc < 2; fc++) {
        s8v bF = ldsB(s_t, fc*32 + c32, ks*16 + h*8, 9);
        acc1[0][fc] = MFMA32(a0, bF, acc1[0][fc]);
        acc1[1][fc] = MFMA32(a1, bF, acc1[1][fc]);
      }
    }
    __syncthreads();   // previous chunk's layer-2 hid_t reads done
#pragma unroll
    for (int ri = 0; ri < 2; ri++) {
      const int rbg = c*8 + w + ri*4;
#pragma unroll
      for (int q = 0; q < 4; q++) {
        int hg0 = rbg*32 + q*8 + 4*h;
        float4 sc = *(const float4*)(sav + hg0);
        float4 of = *(const float4*)(oav + hg0);
        int hl0 = (w + ri*4)*32 + q*8 + 4*h;
#pragma unroll
        for (int fc = 0; fc < 2; fc++) {
          float v0 = fmaxf(acc1[ri][fc][q*4+0]*sc.x + of.x, 0.f);
          float v1 = fmaxf(acc1[ri][fc][q*4+1]*sc.y + of.y, 0.f);
          float v2 = fmaxf(acc1[ri][fc][q*4+2]*sc.z + of.z, 0.f);
          float v3 = fmaxf(acc1[ri][fc][q*4+3]*sc.w + of.w, 0.f);
          st2(hid_t, fc*32 + c32, hl0, 9, v0, v1, v2, v3);
        }
      }
    }
    __syncthreads();   // hid chunk ready
    // layer 2: K=256 over hid_t; global k index = c*256 + klocal
#pragma unroll
    for (int ks = 0; ks < 16; ks++) {
      s8v a0 = ldpk(aw2pk, w*2 + 0, 64, c*16 + ks, l);
      s8v a1 = ldpk(aw2pk, w*2 + 1, 64, c*16 + ks, l);
#pragma unroll
      for (int fc = 0; fc < 2; fc++) {
        s8v bF = ldsB(hid_t, fc*32 + c32, ks*16 + h*8, 9);
        acc2[0][fc] = MFMA32(a0, bF, acc2[0][fc]);
        acc2[1][fc] = MFMA32(a1, bF, acc2[1][fc]);
      }
    }
  }

  // ---- softmax over k (width-16 xor within c32&15) + aggregation ----
#pragma unroll
  for (int fr = 0; fr < 2; fr++)
#pragma unroll
  for (int fc = 0; fc < 2; fc++) {
    int p = fc*2 + (c32 >> 4), kk = c32 & 15;
    int j = knnB[(size_t)(pi0 + p)*KNN_ + kk];
    const float* qp = kqvB + (size_t)(pi0 + p)*LKV + 256;
    const float* kp = kqvB + (size_t)j*LKV;
    const float* vp = kqvB + (size_t)(pi0 + p)*LKV + 512;
#pragma unroll
    for (int q = 0; q < 4; q++) {
      int ch0 = w*64 + fr*32 + q*8 + 4*h;
      float q4[4], k4[4], v4[4], s4[4], res[4];
      *(float4*)q4 = *(const float4*)(qp + ch0);
      *(float4*)k4 = *(const float4*)(kp + ch0);
      *(float4*)v4 = *(const float4*)(vp + ch0);
      ld4s(s_t, fc*32 + c32, ch0, 9, s4);
#pragma unroll
      for (int r = 0; r < 4; r++) {
        float a = acc2[fr][fc][q*4+r];
        float m = a;
        m = fmaxf(m, __shfl_xor(m, 1, 16)); m = fmaxf(m, __shfl_xor(m, 2, 16));
        m = fmaxf(m, __shfl_xor(m, 4, 16)); m = fmaxf(m, __shfl_xor(m, 8, 16));
        float ex = __expf(a - m);
        float se = ex;
        se += __shfl_xor(se, 1, 16); se += __shfl_xor(se, 2, 16);
        se += __shfl_xor(se, 4, 16); se += __shfl_xor(se, 8, 16);
        float watt = ex / se;
        float ve = v4[r] - q4[r] + k4[r] + s4[r];
        float cc = watt * ve;
        cc += __shfl_xor(cc, 1, 16); cc += __shfl_xor(cc, 2, 16);
        cc += __shfl_xor(cc, 4, 16); cc += __shfl_xor(cc, 8, 16);
        res[r] = cc;
      }
      if (kk == 0)
        *(float4*)(aggT + ((size_t)(b*NP) + pi0 + p)*DC + ch0) =
            make_float4(res[0], res[1], res[2], res[3]);
    }
  }
}

// ---------------- launch ----------------
extern "C" void kernel_launch(void* const* d_in, const int* in_sizes, int n_in,
                              void* d_out, int out_size, void* d_ws, size_t ws_size,
                              hipStream_t stream)
{
  const float* x        = (const float*)d_in[0];
  const float* pos      = (const float*)d_in[1];
  const float* P_anchor = (const float*)d_in[3];
  const int*   map_idx  = (const int*)  d_in[4];
  const float* adist    = (const float*)d_in[5];
  const float* w_start  = (const float*)d_in[6];
  const float* b_start  = (const float*)d_in[7];
  const float* w_key    = (const float*)d_in[8];
  const float* b_key    = (const float*)d_in[9];
  const float* w_query  = (const float*)d_in[10];
  const float* b_query  = (const float*)d_in[11];
  const float* w_value  = (const float*)d_in[12];
  const float* b_value  = (const float*)d_in[13];
  const float* pw1      = (const float*)d_in[14];
  const float* pb1      = (const float*)d_in[15];
  const float* pg1      = (const float*)d_in[16];
  const float* pbt1     = (const float*)d_in[17];
  const float* pw2      = (const float*)d_in[18];
  const float* pb2      = (const float*)d_in[19];
  const float* lw1      = (const float*)d_in[20];
  const float* lw2      = (const float*)d_in[21];
  const float* lw3      = (const float*)d_in[22];
  const float* aw1      = (const float*)d_in[23];
  const float* ab1      = (const float*)d_in[24];
  const float* ag1      = (const float*)d_in[25];
  const float* abt1     = (const float*)d_in[26];
  const float* aw2      = (const float*)d_in[27];
  const float* ab2      = (const float*)d_in[28];
  const float* w_end    = (const float*)d_in[29];
  const float* b_end    = (const float*)d_in[30];

  if (ws_size < (size_t)4672384 * 4) return;   // 18.7 MB (ws proven >= 23.4 MB)

  float* ws     = (float*)d_ws;
  float* xf     = ws + 0;               // (b,256,2048) f32; dead after kqv gemm
  float* aggT   = ws + 0;               // aliases xf
  float* kqvT   = ws + 1048576;         // (b,2048,768) f32 interleaved K|Q|V -> ends 4194304
  u16*   aw1pk  = (u16*)(ws + 4194304); // 262144 u16 = 131072 f -> 4325376
  u16*   aw2pk  = (u16*)(ws + 4325376); // 262144 u16 -> 4456448
  u16*   wppk   = (u16*)(ws + 4456448); // 32768 u16 = 16384 f -> 4472832
  u16*   wstpk  = (u16*)(ws + 4472832); // 32768 u16 -> 4489216
  u16*   wkqvpk = (u16*)(ws + 4489216); // 196608 u16 = 98304 f -> 4587520
  u16*   wendpk = (u16*)(ws + 4587520); // 32768 u16 -> 4603904
  float* sa     = ws + 4603904;         // 1024 -> 4604928
  float* oa     = ws + 4604928;         // 1024 -> 4605952
  float* sp     = ws + 4605952;         // 64   -> 4606016
  float* op_    = ws + 4606016;         // 64   -> 4606080
  float* bkqv   = ws + 4606080;         // 768  -> 4606848
  int*   knn_i  = (int*)(ws + 4606848); // 65536 ints -> 4672384
  // end: 4672384 floats

  prep_kernel<<<3208, 256, 0, stream>>>(aw1, aw2, lw3, pw2,
      w_start, w_key, w_query, w_value, w_end, b_key, b_query, b_value,
      ag1, ab1, abt1, pg1, pb1, pbt1,
      aw1pk, aw2pk, wppk, wstpk, wkqvpk, wendpk, sa, oa, sp, op_, bkqv);

  // xf = w_start @ x + b_start   (b,256,2048)
  mgemm<false, false, false><<<dim3(32, 2, 2), 256, 0, stream>>>(
      wstpk, x, b_start, nullptr, xf, 256, NP, 128, 0);

  knn_kernel<<<256, 1024, 0, stream>>>(pos, knn_i);

  // kqvT[n][0:256]=key, [256:512]=query, [512:768]=value
  mgemm<false, true, false><<<dim3(32, 6, 2), 256, 0, stream>>>(
      wkqvpk, xf, bkqv, nullptr, kqvT, 768, NP, 256, LKV);

  fused_attn<<<1024, 256, 0, stream>>>(kqvT, knn_i,
      pos, map_idx, P_anchor, adist,
      lw1, lw2, pw1, sp, op_, pb2,
      aw1pk, sa, oa, aw2pk, wppk, ab2, aggT);

  // out = w_end @ agg + b_end + x
  mgemm<true, false, true><<<dim3(32, 1, 2), 256, 0, stream>>>(
      wendpk, aggT, b_end, x, (float*)d_out, 128, NP, 256, 0);
}

// Round 11
// 233.632 us; speedup vs baseline: 1.1708x; 1.1708x over previous
//
#include <hip/hip_runtime.h>
#include <hip/hip_bf16.h>

typedef __hip_bfloat16 bf16;
typedef unsigned short u16;
typedef __attribute__((ext_vector_type(8))) short s8v;    // 8 bf16 (4 VGPRs) MFMA frag
typedef __attribute__((ext_vector_type(4))) float f32x4;  // MFMA acc frag

#define NP    2048
#define DC    256
#define MA    128
#define KNN_  16
#define LKV   768   // merged K|Q|V row stride

#define MFMA_B16(a,b,c) __builtin_amdgcn_mfma_f32_16x16x32_bf16(a,b,c,0,0,0)

__device__ __forceinline__ float u2f(u16 u){ return __uint_as_float(((unsigned int)u)<<16); }
__device__ __forceinline__ u16 f2u(float f){ bf16 h=__float2bfloat16(f); u16 us; __builtin_memcpy(&us,&h,2); return us; }

// packed A-frag load: layout [((rb*KS+ks)*64+l)*8 + j]
__device__ __forceinline__ s8v ldpk(const u16* pk, int rb, int KS, int ks, int l){
  return *(const s8v*)(pk + (((size_t)((rb*KS + ks)*64 + l))<<3));
}
// LDS B-frag read, 16B, XOR-swizzled. rshift = log2(row bytes)
__device__ __forceinline__ s8v ldsB(const u16* base, int col, int k0, int rshift){
  int byte = ((col<<rshift) + (k0<<1)) ^ ((col&7)<<4);
  return *(const s8v*)((const char*)base + byte);
}
// LDS 4x bf16 write (8B), swizzled
__device__ __forceinline__ void st2(u16* base, int col, int ch0, int rshift,
                                    float v0, float v1, float v2, float v3){
  uint2 pkv;
  pkv.x = (unsigned)f2u(v0) | ((unsigned)f2u(v1)<<16);
  pkv.y = (unsigned)f2u(v2) | ((unsigned)f2u(v3)<<16);
  int byte = ((col<<rshift) + (ch0<<1)) ^ ((col&7)<<4);
  *(uint2*)((char*)base + byte) = pkv;
}
// LDS single bf16 write, swizzled
__device__ __forceinline__ void st1(u16* base, int col, int ch, int rshift, float v){
  int byte = ((col<<rshift) + (ch<<1)) ^ ((col&7)<<4);
  *(u16*)((char*)base + byte) = f2u(v);
}
// LDS 4x bf16 read (8B), swizzled
__device__ __forceinline__ void ld4s(const u16* base, int col, int ch0, int rshift, float* o){
  int byte = ((col<<rshift) + (ch0<<1)) ^ ((col&7)<<4);
  uint2 pkv = *(const uint2*)((const char*)base + byte);
  o[0] = u2f(pkv.x & 0xffff); o[1] = u2f(pkv.x>>16);
  o[2] = u2f(pkv.y & 0xffff); o[3] = u2f(pkv.y>>16);
}

// ---------------- MFMA GEMM (16x16 path, unchanged) ----------------
template<bool XT, bool OT, bool RES>
__global__ __launch_bounds__(256) void mgemm(
    const u16* __restrict__ apk, const float* __restrict__ X,
    const float* __restrict__ bias, const float* __restrict__ resid,
    float* __restrict__ out, int M, int N, int K, int ldo)
{
  __shared__ u16 Bt[64*256];
  const int tid = threadIdx.x;
  const int w = tid>>6, l = tid&63, k = l&15, g = l>>4;
  const int n0 = blockIdx.x*64, m0 = blockIdx.y*128, bb = blockIdx.z;
  const int KS = K >> 5;
  if constexpr (!XT) {
    for (int e = tid*4; e < 64*K; e += 1024) {
      int kk = e >> 6, c = e & 63;
      float4 v = *(const float4*)(X + (size_t)bb*K*N + (size_t)kk*N + n0 + c);
      st1(Bt, c+0, kk, 9, v.x); st1(Bt, c+1, kk, 9, v.y);
      st1(Bt, c+2, kk, 9, v.z); st1(Bt, c+3, kk, 9, v.w);
    }
  } else {
    for (int e = tid*4; e < 64*256; e += 1024) {
      int c = e >> 8, kk = e & 255;
      float4 v = *(const float4*)(X + ((size_t)bb*N + n0 + c)*256 + kk);
      st2(Bt, c, kk, 9, v.x, v.y, v.z, v.w);
    }
  }
  __syncthreads();
  f32x4 acc[2][4] = {};
  const int rbase = (m0>>4) + w*2;
  for (int ks = 0; ks < KS; ks++) {
    s8v a0 = ldpk(apk, rbase,   KS, ks, l);
    s8v a1 = ldpk(apk, rbase+1, KS, ks, l);
#pragma unroll
    for (int cf = 0; cf < 4; cf++) {
      s8v bF = ldsB(Bt, cf*16 + k, ks*32 + g*8, 9);
      acc[0][cf] = MFMA_B16(a0, bF, acc[0][cf]);
      acc[1][cf] = MFMA_B16(a1, bF, acc[1][cf]);
    }
  }
#pragma unroll
  for (int ri = 0; ri < 2; ri++) {
    int mrow = m0 + w*32 + ri*16 + g*4;
#pragma unroll
    for (int r = 0; r < 4; r++) {
      int m = mrow + r;
      float bv = bias[m];
#pragma unroll
      for (int cf = 0; cf < 4; cf++) {
        int n = n0 + cf*16 + k;
        float v = acc[ri][cf][r] + bv;
        if constexpr (RES) v += resid[((size_t)bb*M + m)*N + n];
        if constexpr (OT) out[((size_t)bb*N + n)*ldo + m] = v;
        else              out[((size_t)bb*M + m)*N + n] = v;
      }
    }
  }
}

// ---------------- KNN top-16 (unchanged) ----------------
__global__ __launch_bounds__(1024) void knn_kernel(const float* __restrict__ pos, int* __restrict__ idx)
{
  __shared__ float px[NP], py[NP], pz[NP], pn[NP];
  const int tid = threadIdx.x;
  const int w = tid >> 6, l = tid & 63;
  const int bb = blockIdx.x >> 7;
  const int q0 = (blockIdx.x & 127) * 16;
  const float* pp = pos + (size_t)bb * 3 * NP;
  for (int t = tid; t < NP; t += 1024) {
    float x = pp[t], y = pp[NP + t], z = pp[2*NP + t];
    px[t] = x; py[t] = y; pz[t] = z; pn[t] = x*x + y*y + z*z;
  }
  __syncthreads();
  const int qi = q0 + w;
  const float qx = px[qi], qy = py[qi], qz = pz[qi], qn = pn[qi];
  float bd[16]; int bi[16];
#pragma unroll
  for (int t = 0; t < 16; t++) { bd[t] = 3.4e38f; bi[t] = -1; }
  float worst = 3.4e38f;
  for (int t = 0; t < 32; t++) {
    int j = t*64 + l;
    float d = qn + pn[j] - 2.f * (qx*px[j] + qy*py[j] + qz*pz[j]);
    if (__any(d < worst)) {
      float cd = (d < worst) ? d : 3.4e38f;
      int   cj = j;
#pragma unroll
      for (int s = 0; s < 16; s++) {
        bool sw = cd < bd[s];
        float od = bd[s]; int oj = bi[s];
        bd[s] = sw ? cd : od;  bi[s] = sw ? cj : oj;
        cd    = sw ? od : cd;  cj    = sw ? oj : cj;
      }
      worst = bd[15];
    }
  }
  int myj = 0;
#pragma unroll
  for (int r = 0; r < 16; r++) {
    float md = bd[0]; int mj = bi[0];
#pragma unroll
    for (int o = 1; o < 64; o <<= 1) {
      float od = __shfl_xor(md, o);
      int   oj = __shfl_xor(mj, o);
      bool tk = (od < md) || (od == md && ((unsigned)oj < (unsigned)mj));
      md = tk ? od : md;  mj = tk ? oj : mj;
    }
    if (l == r) myj = mj;
    bool win = (bi[0] == mj);
#pragma unroll
    for (int s = 0; s < 15; s++) {
      bd[s] = win ? bd[s+1] : bd[s];
      bi[s] = win ? bi[s+1] : bi[s];
    }
    bd[15] = win ? 3.4e38f : bd[15];
  }
  if (l < 16) idx[((size_t)bb * NP + qi) * KNN_ + l] = myj;
}

// ---------------- prep: 16x16 packing (reverted from R10's 32x32) ----------------
__global__ __launch_bounds__(256) void prep_kernel(
    const float* __restrict__ aw1, const float* __restrict__ aw2,
    const float* __restrict__ lw3, const float* __restrict__ pw2,
    const float* __restrict__ w_start, const float* __restrict__ w_key,
    const float* __restrict__ w_query, const float* __restrict__ w_value,
    const float* __restrict__ w_end,
    const float* __restrict__ b_key, const float* __restrict__ b_query,
    const float* __restrict__ b_value,
    const float* __restrict__ ag1, const float* __restrict__ ab1, const float* __restrict__ abt1,
    const float* __restrict__ pg1, const float* __restrict__ pb1, const float* __restrict__ pbt1,
    u16* __restrict__ aw1pk, u16* __restrict__ aw2pk, u16* __restrict__ wppk,
    u16* __restrict__ wstpk, u16* __restrict__ wkqvpk, u16* __restrict__ wendpk,
    float* __restrict__ sa, float* __restrict__ oa, float* __restrict__ sp,
    float* __restrict__ op_, float* __restrict__ bkqv)
{
  int i = blockIdx.x * 256 + threadIdx.x;
  const float inv = rsqrtf(1.0f + 1e-5f);
  if (i < 262144) {  // aw1 (1024x256), KS=8
    int rb = i >> 12, rem = i & 4095, ks = rem >> 9, l = (rem >> 3) & 63, j = rem & 7;
    int row = rb*16 + (l & 15), colk = ks*32 + (l >> 4)*8 + j;
    aw1pk[i] = f2u(aw1[(size_t)row*256 + colk]); return;
  }
  i -= 262144;
  if (i < 262144) {  // aw2 (256x1024), KS=32
    int rb = i >> 14, rem = i & 16383, ks = rem >> 9, l = (rem >> 3) & 63, j = rem & 7;
    int row = rb*16 + (l & 15), colk = ks*32 + (l >> 4)*8 + j;
    aw2pk[i] = f2u(aw2[(size_t)row*1024 + colk]); return;
  }
  i -= 262144;
  if (i < 32768) {   // W' = [lw3 | pw2] (256x128), KS=4
    int rb = i >> 11, rem = i & 2047, ks = rem >> 9, l = (rem >> 3) & 63, j = rem & 7;
    int row = rb*16 + (l & 15), colk = ks*32 + (l >> 4)*8 + j;
    float v = (colk < 64) ? lw3[row*64 + colk] : pw2[row*64 + (colk - 64)];
    wppk[i] = f2u(v); return;
  }
  i -= 32768;
  if (i < 32768) {   // w_start (256x128), KS=4
    int rb = i >> 11, rem = i & 2047, ks = rem >> 9, l = (rem >> 3) & 63, j = rem & 7;
    int row = rb*16 + (l & 15), colk = ks*32 + (l >> 4)*8 + j;
    wstpk[i] = f2u(w_start[(size_t)row*128 + colk]); return;
  }
  i -= 32768;
  if (i < 196608) {  // [w_key; w_query; w_value] (768x256), KS=8
    int rb = i >> 12, rem = i & 4095, ks = rem >> 9, l = (rem >> 3) & 63, j = rem & 7;
    int row = rb*16 + (l & 15), colk = ks*32 + (l >> 4)*8 + j;
    float v = (row < 256) ? w_key[(size_t)row*256 + colk]
            : (row < 512) ? w_query[(size_t)(row-256)*256 + colk]
                          : w_value[(size_t)(row-512)*256 + colk];
    wkqvpk[i] = f2u(v); return;
  }
  i -= 196608;
  if (i < 32768) {   // w_end (128x256), KS=8
    int rb = i >> 12, rem = i & 4095, ks = rem >> 9, l = (rem >> 3) & 63, j = rem & 7;
    int row = rb*16 + (l & 15), colk = ks*32 + (l >> 4)*8 + j;
    wendpk[i] = f2u(w_end[(size_t)row*256 + colk]); return;
  }
  i -= 32768;
  if (i < 1024) { float s_ = ag1[i]*inv; sa[i] = s_; oa[i] = ab1[i]*s_ + abt1[i]; return; }
  i -= 1024;
  if (i < 64)  { float s_ = pg1[i]*inv; sp[i] = s_; op_[i] = pb1[i]*s_ + pbt1[i]; return; }
  i -= 64;
  if (i < 768) {
    bkqv[i] = (i < 256) ? b_key[i] : (i < 512) ? b_query[i-256] : b_value[i-512];
  }
}

// ---------------- fused: 16x16 MFMA, hid double-buffer + pipelined chunk loop -------
// 256 thr = 4 waves, 4 points (64 cols). 8 chunks of 128 hidden; per iteration one
// barrier interval contains TWO independent streams: L2(c) on hid[c&1] and L1(c+1)
// into hid[(c+1)&1] -> scheduler can overlap their latencies (R4-R10: 94% stall,
// nothing saturated; this attacks the dependency spine, not occupancy).
// Registers: acc2 64 + acc1 32 + frags (~220 total) < 256 granule -> no spill
// (R10 spilled at ~256: WRITE_SIZE 61MB tripwire).
__global__ __launch_bounds__(256, 2) void fused_attn(
    const float* __restrict__ kqv, const int* __restrict__ knn_idx,
    const float* __restrict__ pos, const int* __restrict__ map_idx,
    const float* __restrict__ P_anchor, const float* __restrict__ adist,
    const float* __restrict__ lw1f, const float* __restrict__ lw2f, const float* __restrict__ pw1f,
    const float* __restrict__ spv, const float* __restrict__ opv, const float* __restrict__ pb2f,
    const u16* __restrict__ aw1pk, const float* __restrict__ sav, const float* __restrict__ oav,
    const u16* __restrict__ aw2pk, const u16* __restrict__ wppk, const float* __restrict__ ab2f,
    float* __restrict__ aggT)
{
  // 64 KiB: s_t [64][256] swz rshift9 (32KB) @0; hid0/hid1 [64][128] rshift8 (16KB each).
  // P0-P2 scratch overlays the (not-yet-written) s_t region; dead before s_t writes.
  __shared__ __align__(16) char smem[65536];
  u16*   s_t   = (u16*)smem;
  u16*   hid0  = (u16*)(smem + 32768);
  u16*   hid1  = (u16*)(smem + 49152);
  float* fFEAT = (float*)smem;               // [4][6][17] f32  (1632 B)
  float* fPREL = (float*)(smem + 1632);      // [4][3][17] f32  (816 B)
  u16*   fH1   = (u16*) (smem + 2448);       // [4][32][17] u16 (4352 B)

  const int tid = threadIdx.x;
  const int w = tid >> 6, l = tid & 63;
  const int k = l & 15, g = l >> 4;
  const int p0 = blockIdx.x * 4;
  const int b = p0 >> 11, pi0 = p0 & 2047;
  const int pi = pi0 + w;
  const int col_w = w*16 + k;

  const float* kqvB = kqv + (size_t)b * NP * LKV;
  const int* knnB = knn_idx + ((size_t)b * NP) * KNN_;

  // ---- P0: geometric features (16 lanes per wave; point = w) ----
  if (l < 16) {
    int kk = l;
    int j = knnB[(size_t)pi * KNN_ + kk];
    const float* pp = pos + (size_t)b * 3 * NP;
    float qx = pp[pi], qy = pp[NP+pi], qz = pp[2*NP+pi];
    float nx = pp[j],  ny = pp[NP+j],  nz = pp[2*NP+j];
    float r1x = qx-nx, r1y = qy-ny, r1z = qz-nz;
    fPREL[(w*3+0)*17+kk] = r1x; fPREL[(w*3+1)*17+kk] = r1y; fPREL[(w*3+2)*17+kk] = r1z;
    int mi = map_idx[b*NP + pi];
    int bj = map_idx[b*NP + j];
    const float* pa = P_anchor + (size_t)b * MA * 3;
    float ax = pa[mi*3], ay = pa[mi*3+1], az = pa[mi*3+2];
    float bx = pa[bj*3], by = pa[bj*3+1], bz = pa[bj*3+2];
    float dA = sqrtf((qx-ax)*(qx-ax)+(qy-ay)*(qy-ay)+(qz-az)*(qz-az));
    float dB = sqrtf((nx-bx)*(nx-bx)+(ny-by)*(ny-by)+(nz-bz)*(nz-bz));
    float dAB = adist[(size_t)b*MA*MA + mi*MA + bj];
    float r2 = dA + dAB + dB;
    fFEAT[(w*6+0)*17+kk] = fabsf(r1x); fFEAT[(w*6+1)*17+kk] = fabsf(r1y);
    fFEAT[(w*6+2)*17+kk] = fabsf(r1z);
    fFEAT[(w*6+3)*17+kk] = r2; fFEAT[(w*6+4)*17+kk] = r2; fFEAT[(w*6+5)*17+kk] = r2;
  }
  __syncthreads();

  // ---- P1: h1 = relu(lw1 @ feats) (32x16 per point) ----
  {
    float f0=fFEAT[(w*6+0)*17+k], f1=fFEAT[(w*6+1)*17+k], f2=fFEAT[(w*6+2)*17+k],
          f3=fFEAT[(w*6+3)*17+k], f4=fFEAT[(w*6+4)*17+k], f5=fFEAT[(w*6+5)*17+k];
#pragma unroll
    for (int jj = 0; jj < 8; jj++) {
      int h = g*8 + jj;
      const float* wp = lw1f + h*6;
      float v = wp[0]*f0 + wp[1]*f1 + wp[2]*f2 + wp[3]*f3 + wp[4]*f4 + wp[5]*f5;
      fH1[(w*32+h)*17+k] = f2u(fmaxf(v, 0.f));
    }
  }
  __syncthreads();

  // ---- P2: h2 -> hid0[col][0..64); ph -> hid0[col][64..128)  (rshift 8) ----
  {
    float hr[32];
#pragma unroll
    for (int t = 0; t < 32; t++) hr[t] = u2f(fH1[(w*32+t)*17+k]);
#pragma unroll
    for (int jj = 0; jj < 16; jj++) {
      int h = g*16 + jj;
      const float4* wp = (const float4*)(lw2f + h*32);
      float a = 0.f;
#pragma unroll
      for (int t4 = 0; t4 < 8; t4++) {
        float4 wv = wp[t4];
        a += wv.x*hr[t4*4] + wv.y*hr[t4*4+1] + wv.z*hr[t4*4+2] + wv.w*hr[t4*4+3];
      }
      st1(hid0, col_w, h, 8, fmaxf(a, 0.f));
    }
    float pr0 = fPREL[(w*3+0)*17+k], pr1 = fPREL[(w*3+1)*17+k], pr2 = fPREL[(w*3+2)*17+k];
#pragma unroll
    for (int jj = 0; jj < 16; jj++) {
      int h = g*16 + jj;
      float d = pw1f[h*3]*pr0 + pw1f[h*3+1]*pr1 + pw1f[h*3+2]*pr2;
      st1(hid0, col_w, 64 + h, 8, fmaxf(d*spv[h] + opv[h], 0.f));
    }
  }
  __syncthreads();

  // ---- s-build: s = (q - k_g + pb2) + W'@H (K=128) via MFMA, write s_t ----
  {
    f32x4 accs[4][4];
#pragma unroll
    for (int fr = 0; fr < 4; fr++) {
      int ch0 = w*64 + fr*16 + g*4;
      const float4 p4 = *(const float4*)(pb2f + ch0);
#pragma unroll
      for (int fc = 0; fc < 4; fc++) {
        int j = knnB[(size_t)(pi0 + fc) * KNN_ + k];
        const float4 q4 = *(const float4*)(kqvB + (size_t)(pi0 + fc)*LKV + 256 + ch0);
        const float4 k4 = *(const float4*)(kqvB + (size_t)j*LKV + ch0);
        accs[fr][fc][0] = q4.x - k4.x + p4.x;
        accs[fr][fc][1] = q4.y - k4.y + p4.y;
        accs[fr][fc][2] = q4.z - k4.z + p4.z;
        accs[fr][fc][3] = q4.w - k4.w + p4.w;
      }
    }
#pragma unroll
    for (int ks = 0; ks < 4; ks++) {
      s8v aF[4];
#pragma unroll
      for (int fr = 0; fr < 4; fr++) aF[fr] = ldpk(wppk, w*4 + fr, 4, ks, l);
#pragma unroll
      for (int fc = 0; fc < 4; fc++) {
        s8v bF = ldsB(hid0, fc*16 + k, ks*32 + g*8, 8);
#pragma unroll
        for (int fr = 0; fr < 4; fr++) accs[fr][fc] = MFMA_B16(aF[fr], bF, accs[fr][fc]);
      }
    }
#pragma unroll
    for (int fr = 0; fr < 4; fr++)
#pragma unroll
      for (int fc = 0; fc < 4; fc++)
        st2(s_t, fc*16 + k, w*64 + fr*16 + g*4, 9,
            accs[fr][fc][0], accs[fr][fc][1], accs[fr][fc][2], accs[fr][fc][3]);
  }
  __syncthreads();   // s_t ready; hid0's H fully consumed

  // ---- acc2 init ----
  f32x4 acc2[4][4];
#pragma unroll
  for (int fr = 0; fr < 4; fr++) {
    const float4 a4 = *(const float4*)(ab2f + w*64 + fr*16 + g*4);
#pragma unroll
    for (int fc = 0; fc < 4; fc++) {
      acc2[fr][fc][0] = a4.x; acc2[fr][fc][1] = a4.y;
      acc2[fr][fc][2] = a4.z; acc2[fr][fc][3] = a4.w;
    }
  }

  // ---- prologue: L1(0) -> hid0 ----
  {
    f32x4 acc1[2][4] = {};
    const int rb0 = w*2;
#pragma unroll
    for (int ks = 0; ks < 8; ks++) {
      s8v a0 = ldpk(aw1pk, rb0,     8, ks, l);
      s8v a1 = ldpk(aw1pk, rb0 + 1, 8, ks, l);
#pragma unroll
      for (int cf = 0; cf < 4; cf++) {
        s8v bF = ldsB(s_t, cf*16 + k, ks*32 + g*8, 9);
        acc1[0][cf] = MFMA_B16(a0, bF, acc1[0][cf]);
        acc1[1][cf] = MFMA_B16(a1, bF, acc1[1][cf]);
      }
    }
#pragma unroll
    for (int ri = 0; ri < 2; ri++) {
      int hl = w*32 + ri*16 + g*4;     // hg = 0*128 + hl
      const float4 sc = *(const float4*)(sav + hl);
      const float4 of = *(const float4*)(oav + hl);
#pragma unroll
      for (int cf = 0; cf < 4; cf++) {
        float v0 = fmaxf(acc1[ri][cf][0]*sc.x + of.x, 0.f);
        float v1 = fmaxf(acc1[ri][cf][1]*sc.y + of.y, 0.f);
        float v2 = fmaxf(acc1[ri][cf][2]*sc.z + of.z, 0.f);
        float v3 = fmaxf(acc1[ri][cf][3]*sc.w + of.w, 0.f);
        st2(hid0, cf*16 + k, hl, 8, v0, v1, v2, v3);
      }
    }
  }
  __syncthreads();   // hid(0) ready

  // ---- pipelined chunk loop: L2(c) on hid[c&1]  ||  L1(c+1) -> hid[(c+1)&1] ----
  for (int c = 0; c < 8; c++) {
    u16* cur = (c & 1) ? hid1 : hid0;
    u16* nxt = (c & 1) ? hid0 : hid1;
    // L2(c): K=128 over cur
#pragma unroll
    for (int ks = 0; ks < 4; ks++) {
      s8v aF[4];
#pragma unroll
      for (int rf = 0; rf < 4; rf++) aF[rf] = ldpk(aw2pk, w*4 + rf, 32, c*4 + ks, l);
#pragma unroll
      for (int cf = 0; cf < 4; cf++) {
        s8v bF = ldsB(cur, cf*16 + k, ks*32 + g*8, 8);
#pragma unroll
        for (int rf = 0; rf < 4; rf++) acc2[rf][cf] = MFMA_B16(aF[rf], bF, acc2[rf][cf]);
      }
    }
    if (c < 7) {
      // L1(c+1): independent of L2(c); writes the other buffer
      f32x4 acc1[2][4] = {};
      const int rb0 = (c+1)*8 + w*2;
#pragma unroll
      for (int ks = 0; ks < 8; ks++) {
        s8v a0 = ldpk(aw1pk, rb0,     8, ks, l);
        s8v a1 = ldpk(aw1pk, rb0 + 1, 8, ks, l);
#pragma unroll
        for (int cf = 0; cf < 4; cf++) {
          s8v bF = ldsB(s_t, cf*16 + k, ks*32 + g*8, 9);
          acc1[0][cf] = MFMA_B16(a0, bF, acc1[0][cf]);
          acc1[1][cf] = MFMA_B16(a1, bF, acc1[1][cf]);
        }
      }
#pragma unroll
      for (int ri = 0; ri < 2; ri++) {
        int hl = w*32 + ri*16 + g*4;
        int hg = (c+1)*128 + hl;
        const float4 sc = *(const float4*)(sav + hg);
        const float4 of = *(const float4*)(oav + hg);
#pragma unroll
        for (int cf = 0; cf < 4; cf++) {
          float v0 = fmaxf(acc1[ri][cf][0]*sc.x + of.x, 0.f);
          float v1 = fmaxf(acc1[ri][cf][1]*sc.y + of.y, 0.f);
          float v2 = fmaxf(acc1[ri][cf][2]*sc.z + of.z, 0.f);
          float v3 = fmaxf(acc1[ri][cf][3]*sc.w + of.w, 0.f);
          st2(nxt, cf*16 + k, hl, 8, v0, v1, v2, v3);
        }
      }
      __syncthreads();   // hid(c+1) ready; hid[c&1] reads (this iter's L2) all done
    }
  }

  // ---- softmax over k (width-16 xor) + aggregation ----
#pragma unroll
  for (int fc = 0; fc < 4; fc++) {
    int j = knnB[(size_t)(pi0 + fc) * KNN_ + k];
    const float* qp = kqvB + (size_t)(pi0 + fc)*LKV + 256;
    const float* kp = kqvB + (size_t)j*LKV;
    const float* vp = kqvB + (size_t)(pi0 + fc)*LKV + 512;
#pragma unroll
    for (int fr = 0; fr < 4; fr++) {
      int ch0 = w*64 + fr*16 + g*4;
      float q4[4], k4[4], v4[4], s4[4], res[4];
      *(float4*)q4 = *(const float4*)(qp + ch0);
      *(float4*)k4 = *(const float4*)(kp + ch0);
      *(float4*)v4 = *(const float4*)(vp + ch0);
      ld4s(s_t, fc*16 + k, ch0, 9, s4);
#pragma unroll
      for (int r = 0; r < 4; r++) {
        float a = acc2[fr][fc][r];
        float m = a;
        m = fmaxf(m, __shfl_xor(m, 1, 16)); m = fmaxf(m, __shfl_xor(m, 2, 16));
        m = fmaxf(m, __shfl_xor(m, 4, 16)); m = fmaxf(m, __shfl_xor(m, 8, 16));
        float ex = __expf(a - m);
        float se = ex;
        se += __shfl_xor(se, 1, 16); se += __shfl_xor(se, 2, 16);
        se += __shfl_xor(se, 4, 16); se += __shfl_xor(se, 8, 16);
        float watt = ex / se;
        float ve = v4[r] - q4[r] + k4[r] + s4[r];
        float cc = watt * ve;
        cc += __shfl_xor(cc, 1, 16); cc += __shfl_xor(cc, 2, 16);
        cc += __shfl_xor(cc, 4, 16); cc += __shfl_xor(cc, 8, 16);
        res[r] = cc;
      }
      if (k == 0)
        *(float4*)(aggT + ((size_t)(b*NP) + pi0 + fc)*DC + ch0) =
            make_float4(res[0], res[1], res[2], res[3]);
    }
  }
}

// ---------------- launch ----------------
extern "C" void kernel_launch(void* const* d_in, const int* in_sizes, int n_in,
                              void* d_out, int out_size, void* d_ws, size_t ws_size,
                              hipStream_t stream)
{
  const float* x        = (const float*)d_in[0];
  const float* pos      = (const float*)d_in[1];
  const float* P_anchor = (const float*)d_in[3];
  const int*   map_idx  = (const int*)  d_in[4];
  const float* adist    = (const float*)d_in[5];
  const float* w_start  = (const float*)d_in[6];
  const float* b_start  = (const float*)d_in[7];
  const float* w_key    = (const float*)d_in[8];
  const float* b_key    = (const float*)d_in[9];
  const float* w_query  = (const float*)d_in[10];
  const float* b_query  = (const float*)d_in[11];
  const float* w_value  = (const float*)d_in[12];
  const float* b_value  = (const float*)d_in[13];
  const float* pw1      = (const float*)d_in[14];
  const float* pb1      = (const float*)d_in[15];
  const float* pg1      = (const float*)d_in[16];
  const float* pbt1     = (const float*)d_in[17];
  const float* pw2      = (const float*)d_in[18];
  const float* pb2      = (const float*)d_in[19];
  const float* lw1      = (const float*)d_in[20];
  const float* lw2      = (const float*)d_in[21];
  const float* lw3      = (const float*)d_in[22];
  const float* aw1      = (const float*)d_in[23];
  const float* ab1      = (const float*)d_in[24];
  const float* ag1      = (const float*)d_in[25];
  const float* abt1     = (const float*)d_in[26];
  const float* aw2      = (const float*)d_in[27];
  const float* ab2      = (const float*)d_in[28];
  const float* w_end    = (const float*)d_in[29];
  const float* b_end    = (const float*)d_in[30];

  if (ws_size < (size_t)4672384 * 4) return;   // 18.7 MB (ws proven >= 23.4 MB)

  float* ws     = (float*)d_ws;
  float* xf     = ws + 0;               // (b,256,2048) f32; dead after kqv gemm
  float* aggT   = ws + 0;               // aliases xf
  float* kqvT   = ws + 1048576;         // (b,2048,768) f32 interleaved K|Q|V -> ends 4194304
  u16*   aw1pk  = (u16*)(ws + 4194304); // 262144 u16 = 131072 f -> 4325376
  u16*   aw2pk  = (u16*)(ws + 4325376); // 262144 u16 -> 4456448
  u16*   wppk   = (u16*)(ws + 4456448); // 32768 u16 = 16384 f -> 4472832
  u16*   wstpk  = (u16*)(ws + 4472832); // 32768 u16 -> 4489216
  u16*   wkqvpk = (u16*)(ws + 4489216); // 196608 u16 = 98304 f -> 4587520
  u16*   wendpk = (u16*)(ws + 4587520); // 32768 u16 -> 4603904
  float* sa     = ws + 4603904;         // 1024 -> 4604928
  float* oa     = ws + 4604928;         // 1024 -> 4605952
  float* sp     = ws + 4605952;         // 64   -> 4606016
  float* op_    = ws + 4606016;         // 64   -> 4606080
  float* bkqv   = ws + 4606080;         // 768  -> 4606848
  int*   knn_i  = (int*)(ws + 4606848); // 65536 ints -> 4672384
  // end: 4672384 floats

  prep_kernel<<<3208, 256, 0, stream>>>(aw1, aw2, lw3, pw2,
      w_start, w_key, w_query, w_value, w_end, b_key, b_query, b_value,
      ag1, ab1, abt1, pg1, pb1, pbt1,
      aw1pk, aw2pk, wppk, wstpk, wkqvpk, wendpk, sa, oa, sp, op_, bkqv);

  // xf = w_start @ x + b_start   (b,256,2048)
  mgemm<false, false, false><<<dim3(32, 2, 2), 256, 0, stream>>>(
      wstpk, x, b_start, nullptr, xf, 256, NP, 128, 0);

  knn_kernel<<<256, 1024, 0, stream>>>(pos, knn_i);

  // kqvT[n][0:256]=key, [256:512]=query, [512:768]=value
  mgemm<false, true, false><<<dim3(32, 6, 2), 256, 0, stream>>>(
      wkqvpk, xf, bkqv, nullptr, kqvT, 768, NP, 256, LKV);

  fused_attn<<<1024, 256, 0, stream>>>(kqvT, knn_i,
      pos, map_idx, P_anchor, adist,
      lw1, lw2, pw1, sp, op_, pb2,
      aw1pk, sa, oa, aw2pk, wppk, ab2, aggT);

  // out = w_end @ agg + b_end + x
  mgemm<true, false, true><<<dim3(32, 1, 2), 256, 0, stream>>>(
      wendpk, aggT, b_end, x, (float*)d_out, 128, NP, 256, 0);
}

// Round 12
// 224.668 us; speedup vs baseline: 1.2175x; 1.0399x over previous
//
#include <hip/hip_runtime.h>
#include <hip/hip_bf16.h>

typedef __hip_bfloat16 bf16;
typedef unsigned short u16;
typedef __attribute__((ext_vector_type(8))) short s8v;    // 8 bf16 (4 VGPRs) MFMA frag
typedef __attribute__((ext_vector_type(4))) float f32x4;  // MFMA acc frag

#define NP    2048
#define DC    256
#define MA    128
#define KNN_  16
#define LKV   768   // merged K|Q|V row stride

#define MFMA_B16(a,b,c) __builtin_amdgcn_mfma_f32_16x16x32_bf16(a,b,c,0,0,0)

__device__ __forceinline__ float u2f(u16 u){ return __uint_as_float(((unsigned int)u)<<16); }
__device__ __forceinline__ u16 f2u(float f){ bf16 h=__float2bfloat16(f); u16 us; __builtin_memcpy(&us,&h,2); return us; }

// packed A-frag load (global): layout [((rb*KS+ks)*64+l)*8 + j]
__device__ __forceinline__ s8v ldpk(const u16* pk, int rb, int KS, int ks, int l){
  return *(const s8v*)(pk + (((size_t)((rb*KS + ks)*64 + l))<<3));
}

// ---- fragment-linear LDS layout ----
// frag (cf, ks) = 1KB at ((cf*NKS+ks)<<10); lane l's 16B at + (l<<4).
// element (col, ch): cf=col>>4, ks=ch>>5, lane=(((ch>>3)&3)<<4)|(col&15), j=ch&7.
// B-frag reads are lane-linear -> conflict-free, zero per-read VALU (imm offsets).
__device__ __forceinline__ s8v ldF(const u16* base, int cf, int ks, int NKS, int l){
  return *(const s8v*)((const char*)base + (((cf*NKS + ks)<<10) | (l<<4)));
}
__device__ __forceinline__ int faddr(int col, int ch, int NKS){
  int cf = col>>4, ks = ch>>5, lane = (((ch>>3)&3)<<4)|(col&15), j = ch&7;
  return ((cf*NKS + ks)<<10) + (lane<<4) + (j<<1);
}
// 4-consecutive-ch store (ch0 % 4 == 0 -> j in {0,4} -> 8B aligned)
__device__ __forceinline__ void stF4(u16* base, int col, int ch0, int NKS,
                                     float v0, float v1, float v2, float v3){
  uint2 pkv;
  pkv.x = (unsigned)f2u(v0) | ((unsigned)f2u(v1)<<16);
  pkv.y = (unsigned)f2u(v2) | ((unsigned)f2u(v3)<<16);
  *(uint2*)((char*)base + faddr(col, ch0, NKS)) = pkv;
}
__device__ __forceinline__ void stF1(u16* base, int col, int ch, int NKS, float v){
  *(u16*)((char*)base + faddr(col, ch, NKS)) = f2u(v);
}
__device__ __forceinline__ void ldF4(const u16* base, int col, int ch0, int NKS, float* o){
  uint2 pkv = *(const uint2*)((const char*)base + faddr(col, ch0, NKS));
  o[0] = u2f(pkv.x & 0xffff); o[1] = u2f(pkv.x>>16);
  o[2] = u2f(pkv.y & 0xffff); o[3] = u2f(pkv.y>>16);
}

// ---------------- MFMA GEMM (16x16, Bt in fragment-linear layout) ----------------
template<bool XT, bool OT, bool RES>
__global__ __launch_bounds__(256) void mgemm(
    const u16* __restrict__ apk, const float* __restrict__ X,
    const float* __restrict__ bias, const float* __restrict__ resid,
    float* __restrict__ out, int M, int N, int K, int ldo)
{
  __shared__ u16 Bt[64*256];
  const int tid = threadIdx.x;
  const int w = tid>>6, l = tid&63, k = l&15, g = l>>4;
  const int n0 = blockIdx.x*64, m0 = blockIdx.y*128, bb = blockIdx.z;
  const int KS = K >> 5;
  if constexpr (!XT) {
    for (int e = tid*4; e < 64*K; e += 1024) {
      int kk = e >> 6, c = e & 63;
      float4 v = *(const float4*)(X + (size_t)bb*K*N + (size_t)kk*N + n0 + c);
      stF1(Bt, c+0, kk, KS, v.x); stF1(Bt, c+1, kk, KS, v.y);
      stF1(Bt, c+2, kk, KS, v.z); stF1(Bt, c+3, kk, KS, v.w);
    }
  } else {
    for (int e = tid*4; e < 64*256; e += 1024) {
      int c = e >> 8, kk = e & 255;
      float4 v = *(const float4*)(X + ((size_t)bb*N + n0 + c)*256 + kk);
      stF4(Bt, c, kk, KS, v.x, v.y, v.z, v.w);
    }
  }
  __syncthreads();
  f32x4 acc[2][4] = {};
  const int rbase = (m0>>4) + w*2;
  for (int ks = 0; ks < KS; ks++) {
    s8v a0 = ldpk(apk, rbase,   KS, ks, l);
    s8v a1 = ldpk(apk, rbase+1, KS, ks, l);
#pragma unroll
    for (int cf = 0; cf < 4; cf++) {
      s8v bF = ldF(Bt, cf, ks, KS, l);
      acc[0][cf] = MFMA_B16(a0, bF, acc[0][cf]);
      acc[1][cf] = MFMA_B16(a1, bF, acc[1][cf]);
    }
  }
#pragma unroll
  for (int ri = 0; ri < 2; ri++) {
    int mrow = m0 + w*32 + ri*16 + g*4;
#pragma unroll
    for (int r = 0; r < 4; r++) {
      int m = mrow + r;
      float bv = bias[m];
#pragma unroll
      for (int cf = 0; cf < 4; cf++) {
        int n = n0 + cf*16 + k;
        float v = acc[ri][cf][r] + bv;
        if constexpr (RES) v += resid[((size_t)bb*M + m)*N + n];
        if constexpr (OT) out[((size_t)bb*N + n)*ldo + m] = v;
        else              out[((size_t)bb*M + m)*N + n] = v;
      }
    }
  }
}

// ---------------- KNN top-16 (unchanged) ----------------
__global__ __launch_bounds__(1024) void knn_kernel(const float* __restrict__ pos, int* __restrict__ idx)
{
  __shared__ float px[NP], py[NP], pz[NP], pn[NP];
  const int tid = threadIdx.x;
  const int w = tid >> 6, l = tid & 63;
  const int bb = blockIdx.x >> 7;
  const int q0 = (blockIdx.x & 127) * 16;
  const float* pp = pos + (size_t)bb * 3 * NP;
  for (int t = tid; t < NP; t += 1024) {
    float x = pp[t], y = pp[NP + t], z = pp[2*NP + t];
    px[t] = x; py[t] = y; pz[t] = z; pn[t] = x*x + y*y + z*z;
  }
  __syncthreads();
  const int qi = q0 + w;
  const float qx = px[qi], qy = py[qi], qz = pz[qi], qn = pn[qi];
  float bd[16]; int bi[16];
#pragma unroll
  for (int t = 0; t < 16; t++) { bd[t] = 3.4e38f; bi[t] = -1; }
  float worst = 3.4e38f;
  for (int t = 0; t < 32; t++) {
    int j = t*64 + l;
    float d = qn + pn[j] - 2.f * (qx*px[j] + qy*py[j] + qz*pz[j]);
    if (__any(d < worst)) {
      float cd = (d < worst) ? d : 3.4e38f;
      int   cj = j;
#pragma unroll
      for (int s = 0; s < 16; s++) {
        bool sw = cd < bd[s];
        float od = bd[s]; int oj = bi[s];
        bd[s] = sw ? cd : od;  bi[s] = sw ? cj : oj;
        cd    = sw ? od : cd;  cj    = sw ? oj : cj;
      }
      worst = bd[15];
    }
  }
  int myj = 0;
#pragma unroll
  for (int r = 0; r < 16; r++) {
    float md = bd[0]; int mj = bi[0];
#pragma unroll
    for (int o = 1; o < 64; o <<= 1) {
      float od = __shfl_xor(md, o);
      int   oj = __shfl_xor(mj, o);
      bool tk = (od < md) || (od == md && ((unsigned)oj < (unsigned)mj));
      md = tk ? od : md;  mj = tk ? oj : mj;
    }
    if (l == r) myj = mj;
    bool win = (bi[0] == mj);
#pragma unroll
    for (int s = 0; s < 15; s++) {
      bd[s] = win ? bd[s+1] : bd[s];
      bi[s] = win ? bi[s+1] : bi[s];
    }
    bd[15] = win ? 3.4e38f : bd[15];
  }
  if (l < 16) idx[((size_t)bb * NP + qi) * KNN_ + l] = myj;
}

// ---------------- prep: 16x16 packing (unchanged from R11) ----------------
__global__ __launch_bounds__(256) void prep_kernel(
    const float* __restrict__ aw1, const float* __restrict__ aw2,
    const float* __restrict__ lw3, const float* __restrict__ pw2,
    const float* __restrict__ w_start, const float* __restrict__ w_key,
    const float* __restrict__ w_query, const float* __restrict__ w_value,
    const float* __restrict__ w_end,
    const float* __restrict__ b_key, const float* __restrict__ b_query,
    const float* __restrict__ b_value,
    const float* __restrict__ ag1, const float* __restrict__ ab1, const float* __restrict__ abt1,
    const float* __restrict__ pg1, const float* __restrict__ pb1, const float* __restrict__ pbt1,
    u16* __restrict__ aw1pk, u16* __restrict__ aw2pk, u16* __restrict__ wppk,
    u16* __restrict__ wstpk, u16* __restrict__ wkqvpk, u16* __restrict__ wendpk,
    float* __restrict__ sa, float* __restrict__ oa, float* __restrict__ sp,
    float* __restrict__ op_, float* __restrict__ bkqv)
{
  int i = blockIdx.x * 256 + threadIdx.x;
  const float inv = rsqrtf(1.0f + 1e-5f);
  if (i < 262144) {  // aw1 (1024x256), KS=8
    int rb = i >> 12, rem = i & 4095, ks = rem >> 9, l = (rem >> 3) & 63, j = rem & 7;
    int row = rb*16 + (l & 15), colk = ks*32 + (l >> 4)*8 + j;
    aw1pk[i] = f2u(aw1[(size_t)row*256 + colk]); return;
  }
  i -= 262144;
  if (i < 262144) {  // aw2 (256x1024), KS=32
    int rb = i >> 14, rem = i & 16383, ks = rem >> 9, l = (rem >> 3) & 63, j = rem & 7;
    int row = rb*16 + (l & 15), colk = ks*32 + (l >> 4)*8 + j;
    aw2pk[i] = f2u(aw2[(size_t)row*1024 + colk]); return;
  }
  i -= 262144;
  if (i < 32768) {   // W' = [lw3 | pw2] (256x128), KS=4
    int rb = i >> 11, rem = i & 2047, ks = rem >> 9, l = (rem >> 3) & 63, j = rem & 7;
    int row = rb*16 + (l & 15), colk = ks*32 + (l >> 4)*8 + j;
    float v = (colk < 64) ? lw3[row*64 + colk] : pw2[row*64 + (colk - 64)];
    wppk[i] = f2u(v); return;
  }
  i -= 32768;
  if (i < 32768) {   // w_start (256x128), KS=4
    int rb = i >> 11, rem = i & 2047, ks = rem >> 9, l = (rem >> 3) & 63, j = rem & 7;
    int row = rb*16 + (l & 15), colk = ks*32 + (l >> 4)*8 + j;
    wstpk[i] = f2u(w_start[(size_t)row*128 + colk]); return;
  }
  i -= 32768;
  if (i < 196608) {  // [w_key; w_query; w_value] (768x256), KS=8
    int rb = i >> 12, rem = i & 4095, ks = rem >> 9, l = (rem >> 3) & 63, j = rem & 7;
    int row = rb*16 + (l & 15), colk = ks*32 + (l >> 4)*8 + j;
    float v = (row < 256) ? w_key[(size_t)row*256 + colk]
            : (row < 512) ? w_query[(size_t)(row-256)*256 + colk]
                          : w_value[(size_t)(row-512)*256 + colk];
    wkqvpk[i] = f2u(v); return;
  }
  i -= 196608;
  if (i < 32768) {   // w_end (128x256), KS=8
    int rb = i >> 12, rem = i & 4095, ks = rem >> 9, l = (rem >> 3) & 63, j = rem & 7;
    int row = rb*16 + (l & 15), colk = ks*32 + (l >> 4)*8 + j;
    wendpk[i] = f2u(w_end[(size_t)row*256 + colk]); return;
  }
  i -= 32768;
  if (i < 1024) { float s_ = ag1[i]*inv; sa[i] = s_; oa[i] = ab1[i]*s_ + abt1[i]; return; }
  i -= 1024;
  if (i < 64)  { float s_ = pg1[i]*inv; sp[i] = s_; op_[i] = pb1[i]*s_ + pbt1[i]; return; }
  i -= 64;
  if (i < 768) {
    bkqv[i] = (i < 256) ? b_key[i] : (i < 512) ? b_query[i-256] : b_value[i-512];
  }
}

// ---------------- fused: 16x16 MFMA, fragment-linear LDS, dbuf pipeline ----------
// R4-R11 ablation: occupancy x2, 32x32, pipelining all null at ~170us; invariant
// was the swizzled [col][ch] LDS layout whose B-reads are ~8-way bank-conflicted
// (col*rowbytes = 0 mod 128B collapses all columns to one bank set). This round:
// frag-linear layout -> ds_read_b128 is lane-linear (conflict-free, imm offsets).
__global__ __launch_bounds__(256, 2) void fused_attn(
    const float* __restrict__ kqv, const int* __restrict__ knn_idx,
    const float* __restrict__ pos, const int* __restrict__ map_idx,
    const float* __restrict__ P_anchor, const float* __restrict__ adist,
    const float* __restrict__ lw1f, const float* __restrict__ lw2f, const float* __restrict__ pw1f,
    const float* __restrict__ spv, const float* __restrict__ opv, const float* __restrict__ pb2f,
    const u16* __restrict__ aw1pk, const float* __restrict__ sav, const float* __restrict__ oav,
    const u16* __restrict__ aw2pk, const u16* __restrict__ wppk, const float* __restrict__ ab2f,
    float* __restrict__ aggT)
{
  // 64 KiB: s_t frag-linear NKS=8 (32KB) @0; hid0/hid1 frag-linear NKS=4 (16KB each).
  // P0-P2 scratch overlays the (not-yet-written) s_t region; dead before s_t writes.
  __shared__ __align__(16) char smem[65536];
  u16*   s_t   = (u16*)smem;
  u16*   hid0  = (u16*)(smem + 32768);
  u16*   hid1  = (u16*)(smem + 49152);
  float* fFEAT = (float*)smem;               // [4][6][17] f32  (1632 B)
  float* fPREL = (float*)(smem + 1632);      // [4][3][17] f32  (816 B)
  u16*   fH1   = (u16*) (smem + 2448);       // [4][32][17] u16 (4352 B)

  const int tid = threadIdx.x;
  const int w = tid >> 6, l = tid & 63;
  const int k = l & 15, g = l >> 4;
  const int p0 = blockIdx.x * 4;
  const int b = p0 >> 11, pi0 = p0 & 2047;
  const int pi = pi0 + w;
  const int col_w = w*16 + k;

  const float* kqvB = kqv + (size_t)b * NP * LKV;
  const int* knnB = knn_idx + ((size_t)b * NP) * KNN_;

  // ---- P0: geometric features (16 lanes per wave; point = w) ----
  if (l < 16) {
    int kk = l;
    int j = knnB[(size_t)pi * KNN_ + kk];
    const float* pp = pos + (size_t)b * 3 * NP;
    float qx = pp[pi], qy = pp[NP+pi], qz = pp[2*NP+pi];
    float nx = pp[j],  ny = pp[NP+j],  nz = pp[2*NP+j];
    float r1x = qx-nx, r1y = qy-ny, r1z = qz-nz;
    fPREL[(w*3+0)*17+kk] = r1x; fPREL[(w*3+1)*17+kk] = r1y; fPREL[(w*3+2)*17+kk] = r1z;
    int mi = map_idx[b*NP + pi];
    int bj = map_idx[b*NP + j];
    const float* pa = P_anchor + (size_t)b * MA * 3;
    float ax = pa[mi*3], ay = pa[mi*3+1], az = pa[mi*3+2];
    float bx = pa[bj*3], by = pa[bj*3+1], bz = pa[bj*3+2];
    float dA = sqrtf((qx-ax)*(qx-ax)+(qy-ay)*(qy-ay)+(qz-az)*(qz-az));
    float dB = sqrtf((nx-bx)*(nx-bx)+(ny-by)*(ny-by)+(nz-bz)*(nz-bz));
    float dAB = adist[(size_t)b*MA*MA + mi*MA + bj];
    float r2 = dA + dAB + dB;
    fFEAT[(w*6+0)*17+kk] = fabsf(r1x); fFEAT[(w*6+1)*17+kk] = fabsf(r1y);
    fFEAT[(w*6+2)*17+kk] = fabsf(r1z);
    fFEAT[(w*6+3)*17+kk] = r2; fFEAT[(w*6+4)*17+kk] = r2; fFEAT[(w*6+5)*17+kk] = r2;
  }
  __syncthreads();

  // ---- P1: h1 = relu(lw1 @ feats) (32x16 per point) ----
  {
    float f0=fFEAT[(w*6+0)*17+k], f1=fFEAT[(w*6+1)*17+k], f2=fFEAT[(w*6+2)*17+k],
          f3=fFEAT[(w*6+3)*17+k], f4=fFEAT[(w*6+4)*17+k], f5=fFEAT[(w*6+5)*17+k];
#pragma unroll
    for (int jj = 0; jj < 8; jj++) {
      int h = g*8 + jj;
      const float* wp = lw1f + h*6;
      float v = wp[0]*f0 + wp[1]*f1 + wp[2]*f2 + wp[3]*f3 + wp[4]*f4 + wp[5]*f5;
      fH1[(w*32+h)*17+k] = f2u(fmaxf(v, 0.f));
    }
  }
  __syncthreads();

  // ---- P2: h2 -> hid0 ch [0..64); ph -> hid0 ch [64..128)  (NKS=4) ----
  {
    float hr[32];
#pragma unroll
    for (int t = 0; t < 32; t++) hr[t] = u2f(fH1[(w*32+t)*17+k]);
#pragma unroll
    for (int jj = 0; jj < 16; jj++) {
      int h = g*16 + jj;
      const float4* wp = (const float4*)(lw2f + h*32);
      float a = 0.f;
#pragma unroll
      for (int t4 = 0; t4 < 8; t4++) {
        float4 wv = wp[t4];
        a += wv.x*hr[t4*4] + wv.y*hr[t4*4+1] + wv.z*hr[t4*4+2] + wv.w*hr[t4*4+3];
      }
      stF1(hid0, col_w, h, 4, fmaxf(a, 0.f));
    }
    float pr0 = fPREL[(w*3+0)*17+k], pr1 = fPREL[(w*3+1)*17+k], pr2 = fPREL[(w*3+2)*17+k];
#pragma unroll
    for (int jj = 0; jj < 16; jj++) {
      int h = g*16 + jj;
      float d = pw1f[h*3]*pr0 + pw1f[h*3+1]*pr1 + pw1f[h*3+2]*pr2;
      stF1(hid0, col_w, 64 + h, 4, fmaxf(d*spv[h] + opv[h], 0.f));
    }
  }
  __syncthreads();

  // ---- s-build: s = (q - k_g + pb2) + W'@H (K=128) via MFMA, write s_t ----
  {
    f32x4 accs[4][4];
#pragma unroll
    for (int fr = 0; fr < 4; fr++) {
      int ch0 = w*64 + fr*16 + g*4;
      const float4 p4 = *(const float4*)(pb2f + ch0);
#pragma unroll
      for (int fc = 0; fc < 4; fc++) {
        int j = knnB[(size_t)(pi0 + fc) * KNN_ + k];
        const float4 q4 = *(const float4*)(kqvB + (size_t)(pi0 + fc)*LKV + 256 + ch0);
        const float4 k4 = *(const float4*)(kqvB + (size_t)j*LKV + ch0);
        accs[fr][fc][0] = q4.x - k4.x + p4.x;
        accs[fr][fc][1] = q4.y - k4.y + p4.y;
        accs[fr][fc][2] = q4.z - k4.z + p4.z;
        accs[fr][fc][3] = q4.w - k4.w + p4.w;
      }
    }
#pragma unroll
    for (int ks = 0; ks < 4; ks++) {
      s8v aF[4];
#pragma unroll
      for (int fr = 0; fr < 4; fr++) aF[fr] = ldpk(wppk, w*4 + fr, 4, ks, l);
#pragma unroll
      for (int fc = 0; fc < 4; fc++) {
        s8v bF = ldF(hid0, fc, ks, 4, l);
#pragma unroll
        for (int fr = 0; fr < 4; fr++) accs[fr][fc] = MFMA_B16(aF[fr], bF, accs[fr][fc]);
      }
    }
#pragma unroll
    for (int fr = 0; fr < 4; fr++)
#pragma unroll
      for (int fc = 0; fc < 4; fc++)
        stF4(s_t, fc*16 + k, w*64 + fr*16 + g*4, 8,
             accs[fr][fc][0], accs[fr][fc][1], accs[fr][fc][2], accs[fr][fc][3]);
  }
  __syncthreads();   // s_t ready; hid0's H fully consumed

  // ---- acc2 init ----
  f32x4 acc2[4][4];
#pragma unroll
  for (int fr = 0; fr < 4; fr++) {
    const float4 a4 = *(const float4*)(ab2f + w*64 + fr*16 + g*4);
#pragma unroll
    for (int fc = 0; fc < 4; fc++) {
      acc2[fr][fc][0] = a4.x; acc2[fr][fc][1] = a4.y;
      acc2[fr][fc][2] = a4.z; acc2[fr][fc][3] = a4.w;
    }
  }

  // ---- prologue: L1(0) -> hid0 ----
  {
    f32x4 acc1[2][4] = {};
    const int rb0 = w*2;
#pragma unroll
    for (int ks = 0; ks < 8; ks++) {
      s8v a0 = ldpk(aw1pk, rb0,     8, ks, l);
      s8v a1 = ldpk(aw1pk, rb0 + 1, 8, ks, l);
#pragma unroll
      for (int cf = 0; cf < 4; cf++) {
        s8v bF = ldF(s_t, cf, ks, 8, l);
        acc1[0][cf] = MFMA_B16(a0, bF, acc1[0][cf]);
        acc1[1][cf] = MFMA_B16(a1, bF, acc1[1][cf]);
      }
    }
#pragma unroll
    for (int ri = 0; ri < 2; ri++) {
      int hl = w*32 + ri*16 + g*4;     // hg = 0*128 + hl
      const float4 sc = *(const float4*)(sav + hl);
      const float4 of = *(const float4*)(oav + hl);
#pragma unroll
      for (int cf = 0; cf < 4; cf++) {
        float v0 = fmaxf(acc1[ri][cf][0]*sc.x + of.x, 0.f);
        float v1 = fmaxf(acc1[ri][cf][1]*sc.y + of.y, 0.f);
        float v2 = fmaxf(acc1[ri][cf][2]*sc.z + of.z, 0.f);
        float v3 = fmaxf(acc1[ri][cf][3]*sc.w + of.w, 0.f);
        stF4(hid0, cf*16 + k, hl, 4, v0, v1, v2, v3);
      }
    }
  }
  __syncthreads();   // hid(0) ready

  // ---- pipelined chunk loop: L2(c) on hid[c&1]  ||  L1(c+1) -> hid[(c+1)&1] ----
  for (int c = 0; c < 8; c++) {
    u16* cur = (c & 1) ? hid1 : hid0;
    u16* nxt = (c & 1) ? hid0 : hid1;
    // L2(c): K=128 over cur
#pragma unroll
    for (int ks = 0; ks < 4; ks++) {
      s8v aF[4];
#pragma unroll
      for (int rf = 0; rf < 4; rf++) aF[rf] = ldpk(aw2pk, w*4 + rf, 32, c*4 + ks, l);
#pragma unroll
      for (int cf = 0; cf < 4; cf++) {
        s8v bF = ldF(cur, cf, ks, 4, l);
#pragma unroll
        for (int rf = 0; rf < 4; rf++) acc2[rf][cf] = MFMA_B16(aF[rf], bF, acc2[rf][cf]);
      }
    }
    if (c < 7) {
      // L1(c+1): independent of L2(c); writes the other buffer
      f32x4 acc1[2][4] = {};
      const int rb0 = (c+1)*8 + w*2;
#pragma unroll
      for (int ks = 0; ks < 8; ks++) {
        s8v a0 = ldpk(aw1pk, rb0,     8, ks, l);
        s8v a1 = ldpk(aw1pk, rb0 + 1, 8, ks, l);
#pragma unroll
        for (int cf = 0; cf < 4; cf++) {
          s8v bF = ldF(s_t, cf, ks, 8, l);
          acc1[0][cf] = MFMA_B16(a0, bF, acc1[0][cf]);
          acc1[1][cf] = MFMA_B16(a1, bF, acc1[1][cf]);
        }
      }
#pragma unroll
      for (int ri = 0; ri < 2; ri++) {
        int hl = w*32 + ri*16 + g*4;
        int hg = (c+1)*128 + hl;
        const float4 sc = *(const float4*)(sav + hg);
        const float4 of = *(const float4*)(oav + hg);
#pragma unroll
        for (int cf = 0; cf < 4; cf++) {
          float v0 = fmaxf(acc1[ri][cf][0]*sc.x + of.x, 0.f);
          float v1 = fmaxf(acc1[ri][cf][1]*sc.y + of.y, 0.f);
          float v2 = fmaxf(acc1[ri][cf][2]*sc.z + of.z, 0.f);
          float v3 = fmaxf(acc1[ri][cf][3]*sc.w + of.w, 0.f);
          stF4(nxt, cf*16 + k, hl, 4, v0, v1, v2, v3);
        }
      }
      __syncthreads();   // hid(c+1) ready; hid[c&1] reads (this iter's L2) all done
    }
  }

  // ---- softmax over k (width-16 xor) + aggregation ----
#pragma unroll
  for (int fc = 0; fc < 4; fc++) {
    int j = knnB[(size_t)(pi0 + fc) * KNN_ + k];
    const float* qp = kqvB + (size_t)(pi0 + fc)*LKV + 256;
    const float* kp = kqvB + (size_t)j*LKV;
    const float* vp = kqvB + (size_t)(pi0 + fc)*LKV + 512;
#pragma unroll
    for (int fr = 0; fr < 4; fr++) {
      int ch0 = w*64 + fr*16 + g*4;
      float q4[4], k4[4], v4[4], s4[4], res[4];
      *(float4*)q4 = *(const float4*)(qp + ch0);
      *(float4*)k4 = *(const float4*)(kp + ch0);
      *(float4*)v4 = *(const float4*)(vp + ch0);
      ldF4(s_t, fc*16 + k, ch0, 8, s4);
#pragma unroll
      for (int r = 0; r < 4; r++) {
        float a = acc2[fr][fc][r];
        float m = a;
        m = fmaxf(m, __shfl_xor(m, 1, 16)); m = fmaxf(m, __shfl_xor(m, 2, 16));
        m = fmaxf(m, __shfl_xor(m, 4, 16)); m = fmaxf(m, __shfl_xor(m, 8, 16));
        float ex = __expf(a - m);
        float se = ex;
        se += __shfl_xor(se, 1, 16); se += __shfl_xor(se, 2, 16);
        se += __shfl_xor(se, 4, 16); se += __shfl_xor(se, 8, 16);
        float watt = ex / se;
        float ve = v4[r] - q4[r] + k4[r] + s4[r];
        float cc = watt * ve;
        cc += __shfl_xor(cc, 1, 16); cc += __shfl_xor(cc, 2, 16);
        cc += __shfl_xor(cc, 4, 16); cc += __shfl_xor(cc, 8, 16);
        res[r] = cc;
      }
      if (k == 0)
        *(float4*)(aggT + ((size_t)(b*NP) + pi0 + fc)*DC + ch0) =
            make_float4(res[0], res[1], res[2], res[3]);
    }
  }
}

// ---------------- launch ----------------
extern "C" void kernel_launch(void* const* d_in, const int* in_sizes, int n_in,
                              void* d_out, int out_size, void* d_ws, size_t ws_size,
                              hipStream_t stream)
{
  const float* x        = (const float*)d_in[0];
  const float* pos      = (const float*)d_in[1];
  const float* P_anchor = (const float*)d_in[3];
  const int*   map_idx  = (const int*)  d_in[4];
  const float* adist    = (const float*)d_in[5];
  const float* w_start  = (const float*)d_in[6];
  const float* b_start  = (const float*)d_in[7];
  const float* w_key    = (const float*)d_in[8];
  const float* b_key    = (const float*)d_in[9];
  const float* w_query  = (const float*)d_in[10];
  const float* b_query  = (const float*)d_in[11];
  const float* w_value  = (const float*)d_in[12];
  const float* b_value  = (const float*)d_in[13];
  const float* pw1      = (const float*)d_in[14];
  const float* pb1      = (const float*)d_in[15];
  const float* pg1      = (const float*)d_in[16];
  const float* pbt1     = (const float*)d_in[17];
  const float* pw2      = (const float*)d_in[18];
  const float* pb2      = (const float*)d_in[19];
  const float* lw1      = (const float*)d_in[20];
  const float* lw2      = (const float*)d_in[21];
  const float* lw3      = (const float*)d_in[22];
  const float* aw1      = (const float*)d_in[23];
  const float* ab1      = (const float*)d_in[24];
  const float* ag1      = (const float*)d_in[25];
  const float* abt1     = (const float*)d_in[26];
  const float* aw2      = (const float*)d_in[27];
  const float* ab2      = (const float*)d_in[28];
  const float* w_end    = (const float*)d_in[29];
  const float* b_end    = (const float*)d_in[30];

  if (ws_size < (size_t)4672384 * 4) return;   // 18.7 MB (ws proven >= 23.4 MB)

  float* ws     = (float*)d_ws;
  float* xf     = ws + 0;               // (b,256,2048) f32; dead after kqv gemm
  float* aggT   = ws + 0;               // aliases xf
  float* kqvT   = ws + 1048576;         // (b,2048,768) f32 interleaved K|Q|V -> ends 4194304
  u16*   aw1pk  = (u16*)(ws + 4194304); // 262144 u16 = 131072 f -> 4325376
  u16*   aw2pk  = (u16*)(ws + 4325376); // 262144 u16 -> 4456448
  u16*   wppk   = (u16*)(ws + 4456448); // 32768 u16 = 16384 f -> 4472832
  u16*   wstpk  = (u16*)(ws + 4472832); // 32768 u16 -> 4489216
  u16*   wkqvpk = (u16*)(ws + 4489216); // 196608 u16 = 98304 f -> 4587520
  u16*   wendpk = (u16*)(ws + 4587520); // 32768 u16 -> 4603904
  float* sa     = ws + 4603904;         // 1024 -> 4604928
  float* oa     = ws + 4604928;         // 1024 -> 4605952
  float* sp     = ws + 4605952;         // 64   -> 4606016
  float* op_    = ws + 4606016;         // 64   -> 4606080
  float* bkqv   = ws + 4606080;         // 768  -> 4606848
  int*   knn_i  = (int*)(ws + 4606848); // 65536 ints -> 4672384
  // end: 4672384 floats

  prep_kernel<<<3208, 256, 0, stream>>>(aw1, aw2, lw3, pw2,
      w_start, w_key, w_query, w_value, w_end, b_key, b_query, b_value,
      ag1, ab1, abt1, pg1, pb1, pbt1,
      aw1pk, aw2pk, wppk, wstpk, wkqvpk, wendpk, sa, oa, sp, op_, bkqv);

  // xf = w_start @ x + b_start   (b,256,2048)
  mgemm<false, false, false><<<dim3(32, 2, 2), 256, 0, stream>>>(
      wstpk, x, b_start, nullptr, xf, 256, NP, 128, 0);

  knn_kernel<<<256, 1024, 0, stream>>>(pos, knn_i);

  // kqvT[n][0:256]=key, [256:512]=query, [512:768]=value
  mgemm<false, true, false><<<dim3(32, 6, 2), 256, 0, stream>>>(
      wkqvpk, xf, bkqv, nullptr, kqvT, 768, NP, 256, LKV);

  fused_attn<<<1024, 256, 0, stream>>>(kqvT, knn_i,
      pos, map_idx, P_anchor, adist,
      lw1, lw2, pw1, sp, op_, pb2,
      aw1pk, sa, oa, aw2pk, wppk, ab2, aggT);

  // out = w_end @ agg + b_end + x
  mgemm<true, false, true><<<dim3(32, 1, 2), 256, 0, stream>>>(
      wendpk, aggT, b_end, x, (float*)d_out, 128, NP, 256, 0);
}

// Round 13
// 209.233 us; speedup vs baseline: 1.3073x; 1.0738x over previous
//
#include <hip/hip_runtime.h>
#include <hip/hip_bf16.h>

typedef __hip_bfloat16 bf16;
typedef unsigned short u16;
typedef __attribute__((ext_vector_type(8))) short s8v;    // 8 bf16 (4 VGPRs) MFMA frag
typedef __attribute__((ext_vector_type(4))) float f32x4;  // MFMA acc frag

#define NP    2048
#define DC    256
#define MA    128
#define KNN_  16
#define LKV   768   // merged K|Q|V row stride

#define MFMA_B16(a,b,c) __builtin_amdgcn_mfma_f32_16x16x32_bf16(a,b,c,0,0,0)

__device__ __forceinline__ float u2f(u16 u){ return __uint_as_float(((unsigned int)u)<<16); }
__device__ __forceinline__ u16 f2u(float f){ bf16 h=__float2bfloat16(f); u16 us; __builtin_memcpy(&us,&h,2); return us; }

// packed A-frag load (global): layout [((rb*KS+ks)*64+l)*8 + j]
__device__ __forceinline__ s8v ldpk(const u16* pk, int rb, int KS, int ks, int l){
  return *(const s8v*)(pk + (((size_t)((rb*KS + ks)*64 + l))<<3));
}

// ---- fragment-linear LDS layout ----
// frag (cf, ks) = 1KB at ((cf*NKS+ks)<<10); lane l's 16B at + (l<<4).
// element (col, ch): cf=col>>4, ks=ch>>5, lane=(((ch>>3)&3)<<4)|(col&15), j=ch&7.
__device__ __forceinline__ s8v ldF(const u16* base, int cf, int ks, int NKS, int l){
  return *(const s8v*)((const char*)base + (((cf*NKS + ks)<<10) | (l<<4)));
}
__device__ __forceinline__ int faddr(int col, int ch, int NKS){
  int cf = col>>4, ks = ch>>5, lane = (((ch>>3)&3)<<4)|(col&15), j = ch&7;
  return ((cf*NKS + ks)<<10) + (lane<<4) + (j<<1);
}
__device__ __forceinline__ void stF4(u16* base, int col, int ch0, int NKS,
                                     float v0, float v1, float v2, float v3){
  uint2 pkv;
  pkv.x = (unsigned)f2u(v0) | ((unsigned)f2u(v1)<<16);
  pkv.y = (unsigned)f2u(v2) | ((unsigned)f2u(v3)<<16);
  *(uint2*)((char*)base + faddr(col, ch0, NKS)) = pkv;
}
__device__ __forceinline__ void stF1(u16* base, int col, int ch, int NKS, float v){
  *(u16*)((char*)base + faddr(col, ch, NKS)) = f2u(v);
}
__device__ __forceinline__ void ldF4(const u16* base, int col, int ch0, int NKS, float* o){
  uint2 pkv = *(const uint2*)((const char*)base + faddr(col, ch0, NKS));
  o[0] = u2f(pkv.x & 0xffff); o[1] = u2f(pkv.x>>16);
  o[2] = u2f(pkv.y & 0xffff); o[3] = u2f(pkv.y>>16);
}

// ---------------- fused w_start + KQV GEMM ----------------
// Stage 1: xf-tile (256 x 64) = wstpk @ x-tile + b_start, kept in LDS (bf16).
// Stage 2: kqv rows [m0,+128) = wkqvpk @ xf-tile + bkqv -> kqvT (b,N,768).
// Removes the separate w_start kernel + xf global roundtrip.
__global__ __launch_bounds__(256) void kqv_fused(
    const u16* __restrict__ wstpk, const float* __restrict__ b_start,
    const u16* __restrict__ wkqvpk, const float* __restrict__ bkqv,
    const float* __restrict__ x, float* __restrict__ kqvT)
{
  __shared__ u16 Bx[64*128];   // x tile, frag-linear NKS=4 (16KB)
  __shared__ u16 Bt[64*256];   // xf tile, frag-linear NKS=8 (32KB)
  const int tid = threadIdx.x;
  const int w = tid>>6, l = tid&63, k = l&15, g = l>>4;
  const int n0 = blockIdx.x*64, m0 = blockIdx.y*128, bb = blockIdx.z;
  // stage 0: x (b,128,2048) tile -> Bx
  for (int e = tid*4; e < 64*128; e += 1024) {
    int kk = e >> 6, c = e & 63;
    float4 v = *(const float4*)(x + (size_t)bb*128*NP + (size_t)kk*NP + n0 + c);
    stF1(Bx, c+0, kk, 4, v.x); stF1(Bx, c+1, kk, 4, v.y);
    stF1(Bx, c+2, kk, 4, v.z); stF1(Bx, c+3, kk, 4, v.w);
  }
  __syncthreads();
  // stage 1: wave w -> xf rows [w*64, +64)
  {
    f32x4 accx[4][4];
#pragma unroll
    for (int fr = 0; fr < 4; fr++) {
      int ch0 = w*64 + fr*16 + g*4;
      float4 b4 = *(const float4*)(b_start + ch0);
#pragma unroll
      for (int cf = 0; cf < 4; cf++) {
        accx[fr][cf][0] = b4.x; accx[fr][cf][1] = b4.y;
        accx[fr][cf][2] = b4.z; accx[fr][cf][3] = b4.w;
      }
    }
#pragma unroll
    for (int ks = 0; ks < 4; ks++) {
      s8v aF[4];
#pragma unroll
      for (int fr = 0; fr < 4; fr++) aF[fr] = ldpk(wstpk, w*4 + fr, 4, ks, l);
#pragma unroll
      for (int cf = 0; cf < 4; cf++) {
        s8v bF = ldF(Bx, cf, ks, 4, l);
#pragma unroll
        for (int fr = 0; fr < 4; fr++) accx[fr][cf] = MFMA_B16(aF[fr], bF, accx[fr][cf]);
      }
    }
#pragma unroll
    for (int fr = 0; fr < 4; fr++)
#pragma unroll
      for (int cf = 0; cf < 4; cf++)
        stF4(Bt, cf*16 + k, w*64 + fr*16 + g*4, 8,
             accx[fr][cf][0], accx[fr][cf][1], accx[fr][cf][2], accx[fr][cf][3]);
  }
  __syncthreads();
  // stage 2: kqv rows [m0,+128)
  f32x4 acc[2][4] = {};
  const int rbase = (m0>>4) + w*2;
#pragma unroll
  for (int ks = 0; ks < 8; ks++) {
    s8v a0 = ldpk(wkqvpk, rbase,   8, ks, l);
    s8v a1 = ldpk(wkqvpk, rbase+1, 8, ks, l);
#pragma unroll
    for (int cf = 0; cf < 4; cf++) {
      s8v bF = ldF(Bt, cf, ks, 8, l);
      acc[0][cf] = MFMA_B16(a0, bF, acc[0][cf]);
      acc[1][cf] = MFMA_B16(a1, bF, acc[1][cf]);
    }
  }
#pragma unroll
  for (int ri = 0; ri < 2; ri++) {
    int mrow = m0 + w*32 + ri*16 + g*4;
#pragma unroll
    for (int r = 0; r < 4; r++) {
      int m = mrow + r;
      float bv = bkqv[m];
#pragma unroll
      for (int cf = 0; cf < 4; cf++) {
        int n = n0 + cf*16 + k;
        kqvT[((size_t)bb*NP + n)*LKV + m] = acc[ri][cf][r] + bv;
      }
    }
  }
}

// ---------------- MFMA GEMM (16x16, Bt frag-linear) — used for w_end ----------------
template<bool XT, bool OT, bool RES>
__global__ __launch_bounds__(256) void mgemm(
    const u16* __restrict__ apk, const float* __restrict__ X,
    const float* __restrict__ bias, const float* __restrict__ resid,
    float* __restrict__ out, int M, int N, int K, int ldo)
{
  __shared__ u16 Bt[64*256];
  const int tid = threadIdx.x;
  const int w = tid>>6, l = tid&63, k = l&15, g = l>>4;
  const int n0 = blockIdx.x*64, m0 = blockIdx.y*128, bb = blockIdx.z;
  const int KS = K >> 5;
  if constexpr (!XT) {
    for (int e = tid*4; e < 64*K; e += 1024) {
      int kk = e >> 6, c = e & 63;
      float4 v = *(const float4*)(X + (size_t)bb*K*N + (size_t)kk*N + n0 + c);
      stF1(Bt, c+0, kk, KS, v.x); stF1(Bt, c+1, kk, KS, v.y);
      stF1(Bt, c+2, kk, KS, v.z); stF1(Bt, c+3, kk, KS, v.w);
    }
  } else {
    for (int e = tid*4; e < 64*256; e += 1024) {
      int c = e >> 8, kk = e & 255;
      float4 v = *(const float4*)(X + ((size_t)bb*N + n0 + c)*256 + kk);
      stF4(Bt, c, kk, KS, v.x, v.y, v.z, v.w);
    }
  }
  __syncthreads();
  f32x4 acc[2][4] = {};
  const int rbase = (m0>>4) + w*2;
  for (int ks = 0; ks < KS; ks++) {
    s8v a0 = ldpk(apk, rbase,   KS, ks, l);
    s8v a1 = ldpk(apk, rbase+1, KS, ks, l);
#pragma unroll
    for (int cf = 0; cf < 4; cf++) {
      s8v bF = ldF(Bt, cf, ks, KS, l);
      acc[0][cf] = MFMA_B16(a0, bF, acc[0][cf]);
      acc[1][cf] = MFMA_B16(a1, bF, acc[1][cf]);
    }
  }
#pragma unroll
  for (int ri = 0; ri < 2; ri++) {
    int mrow = m0 + w*32 + ri*16 + g*4;
#pragma unroll
    for (int r = 0; r < 4; r++) {
      int m = mrow + r;
      float bv = bias[m];
#pragma unroll
      for (int cf = 0; cf < 4; cf++) {
        int n = n0 + cf*16 + k;
        float v = acc[ri][cf][r] + bv;
        if constexpr (RES) v += resid[((size_t)bb*M + m)*N + n];
        if constexpr (OT) out[((size_t)bb*N + n)*ldo + m] = v;
        else              out[((size_t)bb*M + m)*N + n] = v;
      }
    }
  }
}

// ---------------- KNN top-16 (unchanged) ----------------
__global__ __launch_bounds__(1024) void knn_kernel(const float* __restrict__ pos, int* __restrict__ idx)
{
  __shared__ float px[NP], py[NP], pz[NP], pn[NP];
  const int tid = threadIdx.x;
  const int w = tid >> 6, l = tid & 63;
  const int bb = blockIdx.x >> 7;
  const int q0 = (blockIdx.x & 127) * 16;
  const float* pp = pos + (size_t)bb * 3 * NP;
  for (int t = tid; t < NP; t += 1024) {
    float x = pp[t], y = pp[NP + t], z = pp[2*NP + t];
    px[t] = x; py[t] = y; pz[t] = z; pn[t] = x*x + y*y + z*z;
  }
  __syncthreads();
  const int qi = q0 + w;
  const float qx = px[qi], qy = py[qi], qz = pz[qi], qn = pn[qi];
  float bd[16]; int bi[16];
#pragma unroll
  for (int t = 0; t < 16; t++) { bd[t] = 3.4e38f; bi[t] = -1; }
  float worst = 3.4e38f;
  for (int t = 0; t < 32; t++) {
    int j = t*64 + l;
    float d = qn + pn[j] - 2.f * (qx*px[j] + qy*py[j] + qz*pz[j]);
    if (__any(d < worst)) {
      float cd = (d < worst) ? d : 3.4e38f;
      int   cj = j;
#pragma unroll
      for (int s = 0; s < 16; s++) {
        bool sw = cd < bd[s];
        float od = bd[s]; int oj = bi[s];
        bd[s] = sw ? cd : od;  bi[s] = sw ? cj : oj;
        cd    = sw ? od : cd;  cj    = sw ? oj : cj;
      }
      worst = bd[15];
    }
  }
  int myj = 0;
#pragma unroll
  for (int r = 0; r < 16; r++) {
    float md = bd[0]; int mj = bi[0];
#pragma unroll
    for (int o = 1; o < 64; o <<= 1) {
      float od = __shfl_xor(md, o);
      int   oj = __shfl_xor(mj, o);
      bool tk = (od < md) || (od == md && ((unsigned)oj < (unsigned)mj));
      md = tk ? od : md;  mj = tk ? oj : mj;
    }
    if (l == r) myj = mj;
    bool win = (bi[0] == mj);
#pragma unroll
    for (int s = 0; s < 15; s++) {
      bd[s] = win ? bd[s+1] : bd[s];
      bi[s] = win ? bi[s+1] : bi[s];
    }
    bd[15] = win ? 3.4e38f : bd[15];
  }
  if (l < 16) idx[((size_t)bb * NP + qi) * KNN_ + l] = myj;
}

// ---------------- prep: 16x16 packing (unchanged) ----------------
__global__ __launch_bounds__(256) void prep_kernel(
    const float* __restrict__ aw1, const float* __restrict__ aw2,
    const float* __restrict__ lw3, const float* __restrict__ pw2,
    const float* __restrict__ w_start, const float* __restrict__ w_key,
    const float* __restrict__ w_query, const float* __restrict__ w_value,
    const float* __restrict__ w_end,
    const float* __restrict__ b_key, const float* __restrict__ b_query,
    const float* __restrict__ b_value,
    const float* __restrict__ ag1, const float* __restrict__ ab1, const float* __restrict__ abt1,
    const float* __restrict__ pg1, const float* __restrict__ pb1, const float* __restrict__ pbt1,
    u16* __restrict__ aw1pk, u16* __restrict__ aw2pk, u16* __restrict__ wppk,
    u16* __restrict__ wstpk, u16* __restrict__ wkqvpk, u16* __restrict__ wendpk,
    float* __restrict__ sa, float* __restrict__ oa, float* __restrict__ sp,
    float* __restrict__ op_, float* __restrict__ bkqv)
{
  int i = blockIdx.x * 256 + threadIdx.x;
  const float inv = rsqrtf(1.0f + 1e-5f);
  if (i < 262144) {  // aw1 (1024x256), KS=8
    int rb = i >> 12, rem = i & 4095, ks = rem >> 9, l = (rem >> 3) & 63, j = rem & 7;
    int row = rb*16 + (l & 15), colk = ks*32 + (l >> 4)*8 + j;
    aw1pk[i] = f2u(aw1[(size_t)row*256 + colk]); return;
  }
  i -= 262144;
  if (i < 262144) {  // aw2 (256x1024), KS=32
    int rb = i >> 14, rem = i & 16383, ks = rem >> 9, l = (rem >> 3) & 63, j = rem & 7;
    int row = rb*16 + (l & 15), colk = ks*32 + (l >> 4)*8 + j;
    aw2pk[i] = f2u(aw2[(size_t)row*1024 + colk]); return;
  }
  i -= 262144;
  if (i < 32768) {   // W' = [lw3 | pw2] (256x128), KS=4
    int rb = i >> 11, rem = i & 2047, ks = rem >> 9, l = (rem >> 3) & 63, j = rem & 7;
    int row = rb*16 + (l & 15), colk = ks*32 + (l >> 4)*8 + j;
    float v = (colk < 64) ? lw3[row*64 + colk] : pw2[row*64 + (colk - 64)];
    wppk[i] = f2u(v); return;
  }
  i -= 32768;
  if (i < 32768) {   // w_start (256x128), KS=4
    int rb = i >> 11, rem = i & 2047, ks = rem >> 9, l = (rem >> 3) & 63, j = rem & 7;
    int row = rb*16 + (l & 15), colk = ks*32 + (l >> 4)*8 + j;
    wstpk[i] = f2u(w_start[(size_t)row*128 + colk]); return;
  }
  i -= 32768;
  if (i < 196608) {  // [w_key; w_query; w_value] (768x256), KS=8
    int rb = i >> 12, rem = i & 4095, ks = rem >> 9, l = (rem >> 3) & 63, j = rem & 7;
    int row = rb*16 + (l & 15), colk = ks*32 + (l >> 4)*8 + j;
    float v = (row < 256) ? w_key[(size_t)row*256 + colk]
            : (row < 512) ? w_query[(size_t)(row-256)*256 + colk]
                          : w_value[(size_t)(row-512)*256 + colk];
    wkqvpk[i] = f2u(v); return;
  }
  i -= 196608;
  if (i < 32768) {   // w_end (128x256), KS=8
    int rb = i >> 12, rem = i & 4095, ks = rem >> 9, l = (rem >> 3) & 63, j = rem & 7;
    int row = rb*16 + (l & 15), colk = ks*32 + (l >> 4)*8 + j;
    wendpk[i] = f2u(w_end[(size_t)row*256 + colk]); return;
  }
  i -= 32768;
  if (i < 1024) { float s_ = ag1[i]*inv; sa[i] = s_; oa[i] = ab1[i]*s_ + abt1[i]; return; }
  i -= 1024;
  if (i < 64)  { float s_ = pg1[i]*inv; sp[i] = s_; op_[i] = pb1[i]*s_ + pbt1[i]; return; }
  i -= 64;
  if (i < 768) {
    bkqv[i] = (i < 256) ? b_key[i] : (i < 512) ? b_query[i-256] : b_value[i-512];
  }
}

// ---------------- fused: 16x16 MFMA, frag-linear LDS, dbuf pipeline, setprio -------
__global__ __launch_bounds__(256, 2) void fused_attn(
    const float* __restrict__ kqv, const int* __restrict__ knn_idx,
    const float* __restrict__ pos, const int* __restrict__ map_idx,
    const float* __restrict__ P_anchor, const float* __restrict__ adist,
    const float* __restrict__ lw1f, const float* __restrict__ lw2f, const float* __restrict__ pw1f,
    const float* __restrict__ spv, const float* __restrict__ opv, const float* __restrict__ pb2f,
    const u16* __restrict__ aw1pk, const float* __restrict__ sav, const float* __restrict__ oav,
    const u16* __restrict__ aw2pk, const u16* __restrict__ wppk, const float* __restrict__ ab2f,
    float* __restrict__ aggT)
{
  __shared__ __align__(16) char smem[65536];
  u16*   s_t   = (u16*)smem;
  u16*   hid0  = (u16*)(smem + 32768);
  u16*   hid1  = (u16*)(smem + 49152);
  float* fFEAT = (float*)smem;               // [4][6][17] f32
  float* fPREL = (float*)(smem + 1632);      // [4][3][17] f32
  u16*   fH1   = (u16*) (smem + 2448);       // [4][32][17] u16

  const int tid = threadIdx.x;
  const int w = tid >> 6, l = tid & 63;
  const int k = l & 15, g = l >> 4;
  const int p0 = blockIdx.x * 4;
  const int b = p0 >> 11, pi0 = p0 & 2047;
  const int pi = pi0 + w;
  const int col_w = w*16 + k;

  const float* kqvB = kqv + (size_t)b * NP * LKV;
  const int* knnB = knn_idx + ((size_t)b * NP) * KNN_;

  // ---- P0: geometric features ----
  if (l < 16) {
    int kk = l;
    int j = knnB[(size_t)pi * KNN_ + kk];
    const float* pp = pos + (size_t)b * 3 * NP;
    float qx = pp[pi], qy = pp[NP+pi], qz = pp[2*NP+pi];
    float nx = pp[j],  ny = pp[NP+j],  nz = pp[2*NP+j];
    float r1x = qx-nx, r1y = qy-ny, r1z = qz-nz;
    fPREL[(w*3+0)*17+kk] = r1x; fPREL[(w*3+1)*17+kk] = r1y; fPREL[(w*3+2)*17+kk] = r1z;
    int mi = map_idx[b*NP + pi];
    int bj = map_idx[b*NP + j];
    const float* pa = P_anchor + (size_t)b * MA * 3;
    float ax = pa[mi*3], ay = pa[mi*3+1], az = pa[mi*3+2];
    float bx = pa[bj*3], by = pa[bj*3+1], bz = pa[bj*3+2];
    float dA = sqrtf((qx-ax)*(qx-ax)+(qy-ay)*(qy-ay)+(qz-az)*(qz-az));
    float dB = sqrtf((nx-bx)*(nx-bx)+(ny-by)*(ny-by)+(nz-bz)*(nz-bz));
    float dAB = adist[(size_t)b*MA*MA + mi*MA + bj];
    float r2 = dA + dAB + dB;
    fFEAT[(w*6+0)*17+kk] = fabsf(r1x); fFEAT[(w*6+1)*17+kk] = fabsf(r1y);
    fFEAT[(w*6+2)*17+kk] = fabsf(r1z);
    fFEAT[(w*6+3)*17+kk] = r2; fFEAT[(w*6+4)*17+kk] = r2; fFEAT[(w*6+5)*17+kk] = r2;
  }
  __syncthreads();

  // ---- P1: h1 = relu(lw1 @ feats) ----
  {
    float f0=fFEAT[(w*6+0)*17+k], f1=fFEAT[(w*6+1)*17+k], f2=fFEAT[(w*6+2)*17+k],
          f3=fFEAT[(w*6+3)*17+k], f4=fFEAT[(w*6+4)*17+k], f5=fFEAT[(w*6+5)*17+k];
#pragma unroll
    for (int jj = 0; jj < 8; jj++) {
      int h = g*8 + jj;
      const float* wp = lw1f + h*6;
      float v = wp[0]*f0 + wp[1]*f1 + wp[2]*f2 + wp[3]*f3 + wp[4]*f4 + wp[5]*f5;
      fH1[(w*32+h)*17+k] = f2u(fmaxf(v, 0.f));
    }
  }
  __syncthreads();

  // ---- P2: h2 -> hid0 ch [0..64); ph -> hid0 ch [64..128)  (NKS=4) ----
  {
    float hr[32];
#pragma unroll
    for (int t = 0; t < 32; t++) hr[t] = u2f(fH1[(w*32+t)*17+k]);
#pragma unroll
    for (int jj = 0; jj < 16; jj++) {
      int h = g*16 + jj;
      const float4* wp = (const float4*)(lw2f + h*32);
      float a = 0.f;
#pragma unroll
      for (int t4 = 0; t4 < 8; t4++) {
        float4 wv = wp[t4];
        a += wv.x*hr[t4*4] + wv.y*hr[t4*4+1] + wv.z*hr[t4*4+2] + wv.w*hr[t4*4+3];
      }
      stF1(hid0, col_w, h, 4, fmaxf(a, 0.f));
    }
    float pr0 = fPREL[(w*3+0)*17+k], pr1 = fPREL[(w*3+1)*17+k], pr2 = fPREL[(w*3+2)*17+k];
#pragma unroll
    for (int jj = 0; jj < 16; jj++) {
      int h = g*16 + jj;
      float d = pw1f[h*3]*pr0 + pw1f[h*3+1]*pr1 + pw1f[h*3+2]*pr2;
      stF1(hid0, col_w, 64 + h, 4, fmaxf(d*spv[h] + opv[h], 0.f));
    }
  }
  __syncthreads();

  // ---- s-build: s = (q - k_g + pb2) + W'@H (K=128), write s_t ----
  {
    f32x4 accs[4][4];
#pragma unroll
    for (int fr = 0; fr < 4; fr++) {
      int ch0 = w*64 + fr*16 + g*4;
      const float4 p4 = *(const float4*)(pb2f + ch0);
#pragma unroll
      for (int fc = 0; fc < 4; fc++) {
        int j = knnB[(size_t)(pi0 + fc) * KNN_ + k];
        const float4 q4 = *(const float4*)(kqvB + (size_t)(pi0 + fc)*LKV + 256 + ch0);
        const float4 k4 = *(const float4*)(kqvB + (size_t)j*LKV + ch0);
        accs[fr][fc][0] = q4.x - k4.x + p4.x;
        accs[fr][fc][1] = q4.y - k4.y + p4.y;
        accs[fr][fc][2] = q4.z - k4.z + p4.z;
        accs[fr][fc][3] = q4.w - k4.w + p4.w;
      }
    }
#pragma unroll
    for (int ks = 0; ks < 4; ks++) {
      s8v aF[4];
#pragma unroll
      for (int fr = 0; fr < 4; fr++) aF[fr] = ldpk(wppk, w*4 + fr, 4, ks, l);
#pragma unroll
      for (int fc = 0; fc < 4; fc++) {
        s8v bF = ldF(hid0, fc, ks, 4, l);
#pragma unroll
        for (int fr = 0; fr < 4; fr++) accs[fr][fc] = MFMA_B16(aF[fr], bF, accs[fr][fc]);
      }
    }
#pragma unroll
    for (int fr = 0; fr < 4; fr++)
#pragma unroll
      for (int fc = 0; fc < 4; fc++)
        stF4(s_t, fc*16 + k, w*64 + fr*16 + g*4, 8,
             accs[fr][fc][0], accs[fr][fc][1], accs[fr][fc][2], accs[fr][fc][3]);
  }
  __syncthreads();

  // ---- acc2 init ----
  f32x4 acc2[4][4];
#pragma unroll
  for (int fr = 0; fr < 4; fr++) {
    const float4 a4 = *(const float4*)(ab2f + w*64 + fr*16 + g*4);
#pragma unroll
    for (int fc = 0; fc < 4; fc++) {
      acc2[fr][fc][0] = a4.x; acc2[fr][fc][1] = a4.y;
      acc2[fr][fc][2] = a4.z; acc2[fr][fc][3] = a4.w;
    }
  }

  // ---- prologue: L1(0) -> hid0 ----
  {
    f32x4 acc1[2][4] = {};
    const int rb0 = w*2;
    __builtin_amdgcn_s_setprio(1);
#pragma unroll
    for (int ks = 0; ks < 8; ks++) {
      s8v a0 = ldpk(aw1pk, rb0,     8, ks, l);
      s8v a1 = ldpk(aw1pk, rb0 + 1, 8, ks, l);
#pragma unroll
      for (int cf = 0; cf < 4; cf++) {
        s8v bF = ldF(s_t, cf, ks, 8, l);
        acc1[0][cf] = MFMA_B16(a0, bF, acc1[0][cf]);
        acc1[1][cf] = MFMA_B16(a1, bF, acc1[1][cf]);
      }
    }
    __builtin_amdgcn_s_setprio(0);
#pragma unroll
    for (int ri = 0; ri < 2; ri++) {
      int hl = w*32 + ri*16 + g*4;
      const float4 sc = *(const float4*)(sav + hl);
      const float4 of = *(const float4*)(oav + hl);
#pragma unroll
      for (int cf = 0; cf < 4; cf++) {
        float v0 = fmaxf(acc1[ri][cf][0]*sc.x + of.x, 0.f);
        float v1 = fmaxf(acc1[ri][cf][1]*sc.y + of.y, 0.f);
        float v2 = fmaxf(acc1[ri][cf][2]*sc.z + of.z, 0.f);
        float v3 = fmaxf(acc1[ri][cf][3]*sc.w + of.w, 0.f);
        stF4(hid0, cf*16 + k, hl, 4, v0, v1, v2, v3);
      }
    }
  }
  __syncthreads();

  // ---- pipelined chunk loop: L2(c) on hid[c&1] || L1(c+1) -> hid[(c+1)&1] ----
  for (int c = 0; c < 8; c++) {
    u16* cur = (c & 1) ? hid1 : hid0;
    u16* nxt = (c & 1) ? hid0 : hid1;
    __builtin_amdgcn_s_setprio(1);
#pragma unroll
    for (int ks = 0; ks < 4; ks++) {
      s8v aF[4];
#pragma unroll
      for (int rf = 0; rf < 4; rf++) aF[rf] = ldpk(aw2pk, w*4 + rf, 32, c*4 + ks, l);
#pragma unroll
      for (int cf = 0; cf < 4; cf++) {
        s8v bF = ldF(cur, cf, ks, 4, l);
#pragma unroll
        for (int rf = 0; rf < 4; rf++) acc2[rf][cf] = MFMA_B16(aF[rf], bF, acc2[rf][cf]);
      }
    }
    __builtin_amdgcn_s_setprio(0);
    if (c < 7) {
      f32x4 acc1[2][4] = {};
      const int rb0 = (c+1)*8 + w*2;
      __builtin_amdgcn_s_setprio(1);
#pragma unroll
      for (int ks = 0; ks < 8; ks++) {
        s8v a0 = ldpk(aw1pk, rb0,     8, ks, l);
        s8v a1 = ldpk(aw1pk, rb0 + 1, 8, ks, l);
#pragma unroll
        for (int cf = 0; cf < 4; cf++) {
          s8v bF = ldF(s_t, cf, ks, 8, l);
          acc1[0][cf] = MFMA_B16(a0, bF, acc1[0][cf]);
          acc1[1][cf] = MFMA_B16(a1, bF, acc1[1][cf]);
        }
      }
      __builtin_amdgcn_s_setprio(0);
#pragma unroll
      for (int ri = 0; ri < 2; ri++) {
        int hl = w*32 + ri*16 + g*4;
        int hg = (c+1)*128 + hl;
        const float4 sc = *(const float4*)(sav + hg);
        const float4 of = *(const float4*)(oav + hg);
#pragma unroll
        for (int cf = 0; cf < 4; cf++) {
          float v0 = fmaxf(acc1[ri][cf][0]*sc.x + of.x, 0.f);
          float v1 = fmaxf(acc1[ri][cf][1]*sc.y + of.y, 0.f);
          float v2 = fmaxf(acc1[ri][cf][2]*sc.z + of.z, 0.f);
          float v3 = fmaxf(acc1[ri][cf][3]*sc.w + of.w, 0.f);
          stF4(nxt, cf*16 + k, hl, 4, v0, v1, v2, v3);
        }
      }
      __syncthreads();
    }
  }

  // ---- softmax over k (width-16 xor) + aggregation ----
#pragma unroll
  for (int fc = 0; fc < 4; fc++) {
    int j = knnB[(size_t)(pi0 + fc) * KNN_ + k];
    const float* qp = kqvB + (size_t)(pi0 + fc)*LKV + 256;
    const float* kp = kqvB + (size_t)j*LKV;
    const float* vp = kqvB + (size_t)(pi0 + fc)*LKV + 512;
#pragma unroll
    for (int fr = 0; fr < 4; fr++) {
      int ch0 = w*64 + fr*16 + g*4;
      float q4[4], k4[4], v4[4], s4[4], res[4];
      *(float4*)q4 = *(const float4*)(qp + ch0);
      *(float4*)k4 = *(const float4*)(kp + ch0);
      *(float4*)v4 = *(const float4*)(vp + ch0);
      ldF4(s_t, fc*16 + k, ch0, 8, s4);
#pragma unroll
      for (int r = 0; r < 4; r++) {
        float a = acc2[fr][fc][r];
        float m = a;
        m = fmaxf(m, __shfl_xor(m, 1, 16)); m = fmaxf(m, __shfl_xor(m, 2, 16));
        m = fmaxf(m, __shfl_xor(m, 4, 16)); m = fmaxf(m, __shfl_xor(m, 8, 16));
        float ex = __expf(a - m);
        float se = ex;
        se += __shfl_xor(se, 1, 16); se += __shfl_xor(se, 2, 16);
        se += __shfl_xor(se, 4, 16); se += __shfl_xor(se, 8, 16);
        float watt = ex / se;
        float ve = v4[r] - q4[r] + k4[r] + s4[r];
        float cc = watt * ve;
        cc += __shfl_xor(cc, 1, 16); cc += __shfl_xor(cc, 2, 16);
        cc += __shfl_xor(cc, 4, 16); cc += __shfl_xor(cc, 8, 16);
        res[r] = cc;
      }
      if (k == 0)
        *(float4*)(aggT + ((size_t)(b*NP) + pi0 + fc)*DC + ch0) =
            make_float4(res[0], res[1], res[2], res[3]);
    }
  }
}

// ---------------- launch ----------------
extern "C" void kernel_launch(void* const* d_in, const int* in_sizes, int n_in,
                              void* d_out, int out_size, void* d_ws, size_t ws_size,
                              hipStream_t stream)
{
  const float* x        = (const float*)d_in[0];
  const float* pos      = (const float*)d_in[1];
  const float* P_anchor = (const float*)d_in[3];
  const int*   map_idx  = (const int*)  d_in[4];
  const float* adist    = (const float*)d_in[5];
  const float* w_start  = (const float*)d_in[6];
  const float* b_start  = (const float*)d_in[7];
  const float* w_key    = (const float*)d_in[8];
  const float* b_key    = (const float*)d_in[9];
  const float* w_query  = (const float*)d_in[10];
  const float* b_query  = (const float*)d_in[11];
  const float* w_value  = (const float*)d_in[12];
  const float* b_value  = (const float*)d_in[13];
  const float* pw1      = (const float*)d_in[14];
  const float* pb1      = (const float*)d_in[15];
  const float* pg1      = (const float*)d_in[16];
  const float* pbt1     = (const float*)d_in[17];
  const float* pw2      = (const float*)d_in[18];
  const float* pb2      = (const float*)d_in[19];
  const float* lw1      = (const float*)d_in[20];
  const float* lw2      = (const float*)d_in[21];
  const float* lw3      = (const float*)d_in[22];
  const float* aw1      = (const float*)d_in[23];
  const float* ab1      = (const float*)d_in[24];
  const float* ag1      = (const float*)d_in[25];
  const float* abt1     = (const float*)d_in[26];
  const float* aw2      = (const float*)d_in[27];
  const float* ab2      = (const float*)d_in[28];
  const float* w_end    = (const float*)d_in[29];
  const float* b_end    = (const float*)d_in[30];

  if (ws_size < (size_t)4672384 * 4) return;   // 18.7 MB (ws proven >= 23.4 MB)

  float* ws     = (float*)d_ws;
  float* aggT   = ws + 0;               // (b,2048,256) f32
  float* kqvT   = ws + 1048576;         // (b,2048,768) f32 interleaved K|Q|V
  u16*   aw1pk  = (u16*)(ws + 4194304);
  u16*   aw2pk  = (u16*)(ws + 4325376);
  u16*   wppk   = (u16*)(ws + 4456448);
  u16*   wstpk  = (u16*)(ws + 4472832);
  u16*   wkqvpk = (u16*)(ws + 4489216);
  u16*   wendpk = (u16*)(ws + 4587520);
  float* sa     = ws + 4603904;
  float* oa     = ws + 4604928;
  float* sp     = ws + 4605952;
  float* op_    = ws + 4606016;
  float* bkqv   = ws + 4606080;
  int*   knn_i  = (int*)(ws + 4606848);

  prep_kernel<<<3208, 256, 0, stream>>>(aw1, aw2, lw3, pw2,
      w_start, w_key, w_query, w_value, w_end, b_key, b_query, b_value,
      ag1, ab1, abt1, pg1, pb1, pbt1,
      aw1pk, aw2pk, wppk, wstpk, wkqvpk, wendpk, sa, oa, sp, op_, bkqv);

  knn_kernel<<<256, 1024, 0, stream>>>(pos, knn_i);

  // kqvT = [w_key;w_query;w_value] @ (w_start @ x + b_start) + bkqv  (fused)
  kqv_fused<<<dim3(32, 6, 2), 256, 0, stream>>>(
      wstpk, b_start, wkqvpk, bkqv, x, kqvT);

  fused_attn<<<1024, 256, 0, stream>>>(kqvT, knn_i,
      pos, map_idx, P_anchor, adist,
      lw1, lw2, pw1, sp, op_, pb2,
      aw1pk, sa, oa, aw2pk, wppk, ab2, aggT);

  // out = w_end @ agg + b_end + x
  mgemm<true, false, true><<<dim3(32, 1, 2), 256, 0, stream>>>(
      wendpk, aggT, b_end, x, (float*)d_out, 128, NP, 256, 0);
}

// Round 14
// 198.588 us; speedup vs baseline: 1.3774x; 1.0536x over previous
//
#include <hip/hip_runtime.h>
#include <hip/hip_bf16.h>

typedef __hip_bfloat16 bf16;
typedef unsigned short u16;
typedef __attribute__((ext_vector_type(8))) short s8v;    // 8 bf16 (4 VGPRs) MFMA frag
typedef __attribute__((ext_vector_type(4))) float f32x4;  // MFMA acc frag

#define NP    2048
#define DC    256
#define MA    128
#define KNN_  16
#define LKV   768   // merged K|Q|V row stride

#define MFMA_B16(a,b,c) __builtin_amdgcn_mfma_f32_16x16x32_bf16(a,b,c,0,0,0)

__device__ __forceinline__ float u2f(u16 u){ return __uint_as_float(((unsigned int)u)<<16); }
__device__ __forceinline__ u16 f2u(float f){ bf16 h=__float2bfloat16(f); u16 us; __builtin_memcpy(&us,&h,2); return us; }

// packed A-frag load (global): layout [((rb*KS+ks)*64+l)*8 + j]
__device__ __forceinline__ s8v ldpk(const u16* pk, int rb, int KS, int ks, int l){
  return *(const s8v*)(pk + (((size_t)((rb*KS + ks)*64 + l))<<3));
}

// ---- fragment-linear LDS layout ----
// frag (cf, ks) = 1KB at ((cf*NKS+ks)<<10); lane l's 16B at + (l<<4).
// element (col, ch): cf=col>>4, ks=ch>>5, lane=(((ch>>3)&3)<<4)|(col&15), j=ch&7.
__device__ __forceinline__ s8v ldF(const u16* base, int cf, int ks, int NKS, int l){
  return *(const s8v*)((const char*)base + (((cf*NKS + ks)<<10) | (l<<4)));
}
__device__ __forceinline__ int faddr(int col, int ch, int NKS){
  int cf = col>>4, ks = ch>>5, lane = (((ch>>3)&3)<<4)|(col&15), j = ch&7;
  return ((cf*NKS + ks)<<10) + (lane<<4) + (j<<1);
}
__device__ __forceinline__ void stF4(u16* base, int col, int ch0, int NKS,
                                     float v0, float v1, float v2, float v3){
  uint2 pkv;
  pkv.x = (unsigned)f2u(v0) | ((unsigned)f2u(v1)<<16);
  pkv.y = (unsigned)f2u(v2) | ((unsigned)f2u(v3)<<16);
  *(uint2*)((char*)base + faddr(col, ch0, NKS)) = pkv;
}
__device__ __forceinline__ void stF1(u16* base, int col, int ch, int NKS, float v){
  *(u16*)((char*)base + faddr(col, ch, NKS)) = f2u(v);
}
__device__ __forceinline__ void ldF4(const u16* base, int col, int ch0, int NKS, float* o){
  uint2 pkv = *(const uint2*)((const char*)base + faddr(col, ch0, NKS));
  o[0] = u2f(pkv.x & 0xffff); o[1] = u2f(pkv.x>>16);
  o[2] = u2f(pkv.y & 0xffff); o[3] = u2f(pkv.y>>16);
}

// ---------------- fused w_start + KQV GEMM ----------------
__global__ __launch_bounds__(256) void kqv_fused(
    const u16* __restrict__ wstpk, const float* __restrict__ b_start,
    const u16* __restrict__ wkqvpk, const float* __restrict__ bkqv,
    const float* __restrict__ x, float* __restrict__ kqvT)
{
  __shared__ u16 Bx[64*128];   // x tile, frag-linear NKS=4 (16KB)
  __shared__ u16 Bt[64*256];   // xf tile, frag-linear NKS=8 (32KB)
  const int tid = threadIdx.x;
  const int w = tid>>6, l = tid&63, k = l&15, g = l>>4;
  const int n0 = blockIdx.x*64, m0 = blockIdx.y*128, bb = blockIdx.z;
  for (int e = tid*4; e < 64*128; e += 1024) {
    int kk = e >> 6, c = e & 63;
    float4 v = *(const float4*)(x + (size_t)bb*128*NP + (size_t)kk*NP + n0 + c);
    stF1(Bx, c+0, kk, 4, v.x); stF1(Bx, c+1, kk, 4, v.y);
    stF1(Bx, c+2, kk, 4, v.z); stF1(Bx, c+3, kk, 4, v.w);
  }
  __syncthreads();
  {
    f32x4 accx[4][4];
#pragma unroll
    for (int fr = 0; fr < 4; fr++) {
      int ch0 = w*64 + fr*16 + g*4;
      float4 b4 = *(const float4*)(b_start + ch0);
#pragma unroll
      for (int cf = 0; cf < 4; cf++) {
        accx[fr][cf][0] = b4.x; accx[fr][cf][1] = b4.y;
        accx[fr][cf][2] = b4.z; accx[fr][cf][3] = b4.w;
      }
    }
#pragma unroll
    for (int ks = 0; ks < 4; ks++) {
      s8v aF[4];
#pragma unroll
      for (int fr = 0; fr < 4; fr++) aF[fr] = ldpk(wstpk, w*4 + fr, 4, ks, l);
#pragma unroll
      for (int cf = 0; cf < 4; cf++) {
        s8v bF = ldF(Bx, cf, ks, 4, l);
#pragma unroll
        for (int fr = 0; fr < 4; fr++) accx[fr][cf] = MFMA_B16(aF[fr], bF, accx[fr][cf]);
      }
    }
#pragma unroll
    for (int fr = 0; fr < 4; fr++)
#pragma unroll
      for (int cf = 0; cf < 4; cf++)
        stF4(Bt, cf*16 + k, w*64 + fr*16 + g*4, 8,
             accx[fr][cf][0], accx[fr][cf][1], accx[fr][cf][2], accx[fr][cf][3]);
  }
  __syncthreads();
  f32x4 acc[2][4] = {};
  const int rbase = (m0>>4) + w*2;
#pragma unroll
  for (int ks = 0; ks < 8; ks++) {
    s8v a0 = ldpk(wkqvpk, rbase,   8, ks, l);
    s8v a1 = ldpk(wkqvpk, rbase+1, 8, ks, l);
#pragma unroll
    for (int cf = 0; cf < 4; cf++) {
      s8v bF = ldF(Bt, cf, ks, 8, l);
      acc[0][cf] = MFMA_B16(a0, bF, acc[0][cf]);
      acc[1][cf] = MFMA_B16(a1, bF, acc[1][cf]);
    }
  }
#pragma unroll
  for (int ri = 0; ri < 2; ri++) {
    int mrow = m0 + w*32 + ri*16 + g*4;
#pragma unroll
    for (int r = 0; r < 4; r++) {
      int m = mrow + r;
      float bv = bkqv[m];
#pragma unroll
      for (int cf = 0; cf < 4; cf++) {
        int n = n0 + cf*16 + k;
        kqvT[((size_t)bb*NP + n)*LKV + m] = acc[ri][cf][r] + bv;
      }
    }
  }
}

// ---------------- merged prep + KNN (1024 threads) ----------------
// blocks 0..255: KNN (wave-per-query). blocks 256+: weight prep, i strided by 1024.
__global__ __launch_bounds__(1024) void prep_knn(
    const float* __restrict__ pos, int* __restrict__ idx,
    const float* __restrict__ aw1, const float* __restrict__ aw2,
    const float* __restrict__ lw3, const float* __restrict__ pw2,
    const float* __restrict__ w_start, const float* __restrict__ w_key,
    const float* __restrict__ w_query, const float* __restrict__ w_value,
    const float* __restrict__ w_end,
    const float* __restrict__ b_key, const float* __restrict__ b_query,
    const float* __restrict__ b_value,
    const float* __restrict__ ag1, const float* __restrict__ ab1, const float* __restrict__ abt1,
    const float* __restrict__ pg1, const float* __restrict__ pb1, const float* __restrict__ pbt1,
    u16* __restrict__ aw1pk, u16* __restrict__ aw2pk, u16* __restrict__ wppk,
    u16* __restrict__ wstpk, u16* __restrict__ wkqvpk, u16* __restrict__ wendpk,
    float* __restrict__ sa, float* __restrict__ oa, float* __restrict__ sp,
    float* __restrict__ op_, float* __restrict__ bkqv)
{
  __shared__ float px[NP], py[NP], pz[NP], pn[NP];
  if (blockIdx.x < 256) {
    const int tid = threadIdx.x;
    const int w = tid >> 6, l = tid & 63;
    const int bb = blockIdx.x >> 7;
    const int q0 = (blockIdx.x & 127) * 16;
    const float* pp = pos + (size_t)bb * 3 * NP;
    for (int t = tid; t < NP; t += 1024) {
      float x = pp[t], y = pp[NP + t], z = pp[2*NP + t];
      px[t] = x; py[t] = y; pz[t] = z; pn[t] = x*x + y*y + z*z;
    }
    __syncthreads();
    const int qi = q0 + w;
    const float qx = px[qi], qy = py[qi], qz = pz[qi], qn = pn[qi];
    float bd[16]; int bi[16];
#pragma unroll
    for (int t = 0; t < 16; t++) { bd[t] = 3.4e38f; bi[t] = -1; }
    float worst = 3.4e38f;
    for (int t = 0; t < 32; t++) {
      int j = t*64 + l;
      float d = qn + pn[j] - 2.f * (qx*px[j] + qy*py[j] + qz*pz[j]);
      if (__any(d < worst)) {
        float cd = (d < worst) ? d : 3.4e38f;
        int   cj = j;
#pragma unroll
        for (int s = 0; s < 16; s++) {
          bool sw = cd < bd[s];
          float od = bd[s]; int oj = bi[s];
          bd[s] = sw ? cd : od;  bi[s] = sw ? cj : oj;
          cd    = sw ? od : cd;  cj    = sw ? oj : cj;
        }
        worst = bd[15];
      }
    }
    int myj = 0;
#pragma unroll
    for (int r = 0; r < 16; r++) {
      float md = bd[0]; int mj = bi[0];
#pragma unroll
      for (int o = 1; o < 64; o <<= 1) {
        float od = __shfl_xor(md, o);
        int   oj = __shfl_xor(mj, o);
        bool tk = (od < md) || (od == md && ((unsigned)oj < (unsigned)mj));
        md = tk ? od : md;  mj = tk ? oj : mj;
      }
      if (l == r) myj = mj;
      bool win = (bi[0] == mj);
#pragma unroll
      for (int s = 0; s < 15; s++) {
        bd[s] = win ? bd[s+1] : bd[s];
        bi[s] = win ? bi[s+1] : bi[s];
      }
      bd[15] = win ? 3.4e38f : bd[15];
    }
    if (l < 16) idx[((size_t)bb * NP + qi) * KNN_ + l] = myj;
    return;
  }
  int i = (blockIdx.x - 256) * 1024 + threadIdx.x;
  const float inv = rsqrtf(1.0f + 1e-5f);
  if (i < 262144) {  // aw1 (1024x256), KS=8
    int rb = i >> 12, rem = i & 4095, ks = rem >> 9, l = (rem >> 3) & 63, j = rem & 7;
    int row = rb*16 + (l & 15), colk = ks*32 + (l >> 4)*8 + j;
    aw1pk[i] = f2u(aw1[(size_t)row*256 + colk]); return;
  }
  i -= 262144;
  if (i < 262144) {  // aw2 (256x1024), KS=32
    int rb = i >> 14, rem = i & 16383, ks = rem >> 9, l = (rem >> 3) & 63, j = rem & 7;
    int row = rb*16 + (l & 15), colk = ks*32 + (l >> 4)*8 + j;
    aw2pk[i] = f2u(aw2[(size_t)row*1024 + colk]); return;
  }
  i -= 262144;
  if (i < 32768) {   // W' = [lw3 | pw2] (256x128), KS=4
    int rb = i >> 11, rem = i & 2047, ks = rem >> 9, l = (rem >> 3) & 63, j = rem & 7;
    int row = rb*16 + (l & 15), colk = ks*32 + (l >> 4)*8 + j;
    float v = (colk < 64) ? lw3[row*64 + colk] : pw2[row*64 + (colk - 64)];
    wppk[i] = f2u(v); return;
  }
  i -= 32768;
  if (i < 32768) {   // w_start (256x128), KS=4
    int rb = i >> 11, rem = i & 2047, ks = rem >> 9, l = (rem >> 3) & 63, j = rem & 7;
    int row = rb*16 + (l & 15), colk = ks*32 + (l >> 4)*8 + j;
    wstpk[i] = f2u(w_start[(size_t)row*128 + colk]); return;
  }
  i -= 32768;
  if (i < 196608) {  // [w_key; w_query; w_value] (768x256), KS=8
    int rb = i >> 12, rem = i & 4095, ks = rem >> 9, l = (rem >> 3) & 63, j = rem & 7;
    int row = rb*16 + (l & 15), colk = ks*32 + (l >> 4)*8 + j;
    float v = (row < 256) ? w_key[(size_t)row*256 + colk]
            : (row < 512) ? w_query[(size_t)(row-256)*256 + colk]
                          : w_value[(size_t)(row-512)*256 + colk];
    wkqvpk[i] = f2u(v); return;
  }
  i -= 196608;
  if (i < 32768) {   // w_end (128x256), KS=8
    int rb = i >> 12, rem = i & 4095, ks = rem >> 9, l = (rem >> 3) & 63, j = rem & 7;
    int row = rb*16 + (l & 15), colk = ks*32 + (l >> 4)*8 + j;
    wendpk[i] = f2u(w_end[(size_t)row*256 + colk]); return;
  }
  i -= 32768;
  if (i < 1024) { float s_ = ag1[i]*inv; sa[i] = s_; oa[i] = ab1[i]*s_ + abt1[i]; return; }
  i -= 1024;
  if (i < 64)  { float s_ = pg1[i]*inv; sp[i] = s_; op_[i] = pb1[i]*s_ + pbt1[i]; return; }
  i -= 64;
  if (i < 768) {
    bkqv[i] = (i < 256) ? b_key[i] : (i < 512) ? b_query[i-256] : b_value[i-512];
  }
}

// ---------------- fused: geometric MLPs + attn MLP + softmax + agg + w_end ----------
__global__ __launch_bounds__(256, 2) void fused_attn(
    const float* __restrict__ kqv, const int* __restrict__ knn_idx,
    const float* __restrict__ pos, const int* __restrict__ map_idx,
    const float* __restrict__ P_anchor, const float* __restrict__ adist,
    const float* __restrict__ lw1f, const float* __restrict__ lw2f, const float* __restrict__ pw1f,
    const float* __restrict__ spv, const float* __restrict__ opv, const float* __restrict__ pb2f,
    const u16* __restrict__ aw1pk, const float* __restrict__ sav, const float* __restrict__ oav,
    const u16* __restrict__ aw2pk, const u16* __restrict__ wppk, const float* __restrict__ ab2f,
    const u16* __restrict__ wendpk, const float* __restrict__ b_endv,
    const float* __restrict__ xin, float* __restrict__ outp)
{
  __shared__ __align__(16) char smem[65536];
  u16*   s_t   = (u16*)smem;
  u16*   hid0  = (u16*)(smem + 32768);
  u16*   hid1  = (u16*)(smem + 49152);
  float* fFEAT = (float*)smem;               // [4][6][17] f32
  float* fPREL = (float*)(smem + 1632);      // [4][3][17] f32
  u16*   fH1   = (u16*) (smem + 2448);       // [4][32][17] u16

  const int tid = threadIdx.x;
  const int w = tid >> 6, l = tid & 63;
  const int k = l & 15, g = l >> 4;
  const int p0 = blockIdx.x * 4;
  const int b = p0 >> 11, pi0 = p0 & 2047;
  const int pi = pi0 + w;
  const int col_w = w*16 + k;

  const float* kqvB = kqv + (size_t)b * NP * LKV;
  const int* knnB = knn_idx + ((size_t)b * NP) * KNN_;

  // ---- P0: geometric features ----
  if (l < 16) {
    int kk = l;
    int j = knnB[(size_t)pi * KNN_ + kk];
    const float* pp = pos + (size_t)b * 3 * NP;
    float qx = pp[pi], qy = pp[NP+pi], qz = pp[2*NP+pi];
    float nx = pp[j],  ny = pp[NP+j],  nz = pp[2*NP+j];
    float r1x = qx-nx, r1y = qy-ny, r1z = qz-nz;
    fPREL[(w*3+0)*17+kk] = r1x; fPREL[(w*3+1)*17+kk] = r1y; fPREL[(w*3+2)*17+kk] = r1z;
    int mi = map_idx[b*NP + pi];
    int bj = map_idx[b*NP + j];
    const float* pa = P_anchor + (size_t)b * MA * 3;
    float ax = pa[mi*3], ay = pa[mi*3+1], az = pa[mi*3+2];
    float bx = pa[bj*3], by = pa[bj*3+1], bz = pa[bj*3+2];
    float dA = sqrtf((qx-ax)*(qx-ax)+(qy-ay)*(qy-ay)+(qz-az)*(qz-az));
    float dB = sqrtf((nx-bx)*(nx-bx)+(ny-by)*(ny-by)+(nz-bz)*(nz-bz));
    float dAB = adist[(size_t)b*MA*MA + mi*MA + bj];
    float r2 = dA + dAB + dB;
    fFEAT[(w*6+0)*17+kk] = fabsf(r1x); fFEAT[(w*6+1)*17+kk] = fabsf(r1y);
    fFEAT[(w*6+2)*17+kk] = fabsf(r1z);
    fFEAT[(w*6+3)*17+kk] = r2; fFEAT[(w*6+4)*17+kk] = r2; fFEAT[(w*6+5)*17+kk] = r2;
  }
  __syncthreads();

  // ---- P1: h1 = relu(lw1 @ feats) ----
  {
    float f0=fFEAT[(w*6+0)*17+k], f1=fFEAT[(w*6+1)*17+k], f2=fFEAT[(w*6+2)*17+k],
          f3=fFEAT[(w*6+3)*17+k], f4=fFEAT[(w*6+4)*17+k], f5=fFEAT[(w*6+5)*17+k];
#pragma unroll
    for (int jj = 0; jj < 8; jj++) {
      int h = g*8 + jj;
      const float* wp = lw1f + h*6;
      float v = wp[0]*f0 + wp[1]*f1 + wp[2]*f2 + wp[3]*f3 + wp[4]*f4 + wp[5]*f5;
      fH1[(w*32+h)*17+k] = f2u(fmaxf(v, 0.f));
    }
  }
  __syncthreads();

  // ---- P2: h2 -> hid0 ch [0..64); ph -> hid0 ch [64..128)  (NKS=4) ----
  {
    float hr[32];
#pragma unroll
    for (int t = 0; t < 32; t++) hr[t] = u2f(fH1[(w*32+t)*17+k]);
#pragma unroll
    for (int jj = 0; jj < 16; jj++) {
      int h = g*16 + jj;
      const float4* wp = (const float4*)(lw2f + h*32);
      float a = 0.f;
#pragma unroll
      for (int t4 = 0; t4 < 8; t4++) {
        float4 wv = wp[t4];
        a += wv.x*hr[t4*4] + wv.y*hr[t4*4+1] + wv.z*hr[t4*4+2] + wv.w*hr[t4*4+3];
      }
      stF1(hid0, col_w, h, 4, fmaxf(a, 0.f));
    }
    float pr0 = fPREL[(w*3+0)*17+k], pr1 = fPREL[(w*3+1)*17+k], pr2 = fPREL[(w*3+2)*17+k];
#pragma unroll
    for (int jj = 0; jj < 16; jj++) {
      int h = g*16 + jj;
      float d = pw1f[h*3]*pr0 + pw1f[h*3+1]*pr1 + pw1f[h*3+2]*pr2;
      stF1(hid0, col_w, 64 + h, 4, fmaxf(d*spv[h] + opv[h], 0.f));
    }
  }
  __syncthreads();

  // ---- s-build: s = (q - k_g + pb2) + W'@H (K=128), write s_t ----
  {
    f32x4 accs[4][4];
#pragma unroll
    for (int fr = 0; fr < 4; fr++) {
      int ch0 = w*64 + fr*16 + g*4;
      const float4 p4 = *(const float4*)(pb2f + ch0);
#pragma unroll
      for (int fc = 0; fc < 4; fc++) {
        int j = knnB[(size_t)(pi0 + fc) * KNN_ + k];
        const float4 q4 = *(const float4*)(kqvB + (size_t)(pi0 + fc)*LKV + 256 + ch0);
        const float4 k4 = *(const float4*)(kqvB + (size_t)j*LKV + ch0);
        accs[fr][fc][0] = q4.x - k4.x + p4.x;
        accs[fr][fc][1] = q4.y - k4.y + p4.y;
        accs[fr][fc][2] = q4.z - k4.z + p4.z;
        accs[fr][fc][3] = q4.w - k4.w + p4.w;
      }
    }
#pragma unroll
    for (int ks = 0; ks < 4; ks++) {
      s8v aF[4];
#pragma unroll
      for (int fr = 0; fr < 4; fr++) aF[fr] = ldpk(wppk, w*4 + fr, 4, ks, l);
#pragma unroll
      for (int fc = 0; fc < 4; fc++) {
        s8v bF = ldF(hid0, fc, ks, 4, l);
#pragma unroll
        for (int fr = 0; fr < 4; fr++) accs[fr][fc] = MFMA_B16(aF[fr], bF, accs[fr][fc]);
      }
    }
#pragma unroll
    for (int fr = 0; fr < 4; fr++)
#pragma unroll
      for (int fc = 0; fc < 4; fc++)
        stF4(s_t, fc*16 + k, w*64 + fr*16 + g*4, 8,
             accs[fr][fc][0], accs[fr][fc][1], accs[fr][fc][2], accs[fr][fc][3]);
  }
  __syncthreads();

  // ---- acc2 init ----
  f32x4 acc2[4][4];
#pragma unroll
  for (int fr = 0; fr < 4; fr++) {
    const float4 a4 = *(const float4*)(ab2f + w*64 + fr*16 + g*4);
#pragma unroll
    for (int fc = 0; fc < 4; fc++) {
      acc2[fr][fc][0] = a4.x; acc2[fr][fc][1] = a4.y;
      acc2[fr][fc][2] = a4.z; acc2[fr][fc][3] = a4.w;
    }
  }

  // ---- prologue: L1(0) -> hid0 ----
  {
    f32x4 acc1[2][4] = {};
    const int rb0 = w*2;
    __builtin_amdgcn_s_setprio(1);
#pragma unroll
    for (int ks = 0; ks < 8; ks++) {
      s8v a0 = ldpk(aw1pk, rb0,     8, ks, l);
      s8v a1 = ldpk(aw1pk, rb0 + 1, 8, ks, l);
#pragma unroll
      for (int cf = 0; cf < 4; cf++) {
        s8v bF = ldF(s_t, cf, ks, 8, l);
        acc1[0][cf] = MFMA_B16(a0, bF, acc1[0][cf]);
        acc1[1][cf] = MFMA_B16(a1, bF, acc1[1][cf]);
      }
    }
    __builtin_amdgcn_s_setprio(0);
#pragma unroll
    for (int ri = 0; ri < 2; ri++) {
      int hl = w*32 + ri*16 + g*4;
      const float4 sc = *(const float4*)(sav + hl);
      const float4 of = *(const float4*)(oav + hl);
#pragma unroll
      for (int cf = 0; cf < 4; cf++) {
        float v0 = fmaxf(acc1[ri][cf][0]*sc.x + of.x, 0.f);
        float v1 = fmaxf(acc1[ri][cf][1]*sc.y + of.y, 0.f);
        float v2 = fmaxf(acc1[ri][cf][2]*sc.z + of.z, 0.f);
        float v3 = fmaxf(acc1[ri][cf][3]*sc.w + of.w, 0.f);
        stF4(hid0, cf*16 + k, hl, 4, v0, v1, v2, v3);
      }
    }
  }
  __syncthreads();

  // ---- pipelined chunk loop: L2(c) on hid[c&1] || L1(c+1) -> hid[(c+1)&1] ----
  for (int c = 0; c < 8; c++) {
    u16* cur = (c & 1) ? hid1 : hid0;
    u16* nxt = (c & 1) ? hid0 : hid1;
    __builtin_amdgcn_s_setprio(1);
#pragma unroll
    for (int ks = 0; ks < 4; ks++) {
      s8v aF[4];
#pragma unroll
      for (int rf = 0; rf < 4; rf++) aF[rf] = ldpk(aw2pk, w*4 + rf, 32, c*4 + ks, l);
#pragma unroll
      for (int cf = 0; cf < 4; cf++) {
        s8v bF = ldF(cur, cf, ks, 4, l);
#pragma unroll
        for (int rf = 0; rf < 4; rf++) acc2[rf][cf] = MFMA_B16(aF[rf], bF, acc2[rf][cf]);
      }
    }
    __builtin_amdgcn_s_setprio(0);
    if (c < 7) {
      f32x4 acc1[2][4] = {};
      const int rb0 = (c+1)*8 + w*2;
      __builtin_amdgcn_s_setprio(1);
#pragma unroll
      for (int ks = 0; ks < 8; ks++) {
        s8v a0 = ldpk(aw1pk, rb0,     8, ks, l);
        s8v a1 = ldpk(aw1pk, rb0 + 1, 8, ks, l);
#pragma unroll
        for (int cf = 0; cf < 4; cf++) {
          s8v bF = ldF(s_t, cf, ks, 8, l);
          acc1[0][cf] = MFMA_B16(a0, bF, acc1[0][cf]);
          acc1[1][cf] = MFMA_B16(a1, bF, acc1[1][cf]);
        }
      }
      __builtin_amdgcn_s_setprio(0);
#pragma unroll
      for (int ri = 0; ri < 2; ri++) {
        int hl = w*32 + ri*16 + g*4;
        int hg = (c+1)*128 + hl;
        const float4 sc = *(const float4*)(sav + hg);
        const float4 of = *(const float4*)(oav + hg);
#pragma unroll
        for (int cf = 0; cf < 4; cf++) {
          float v0 = fmaxf(acc1[ri][cf][0]*sc.x + of.x, 0.f);
          float v1 = fmaxf(acc1[ri][cf][1]*sc.y + of.y, 0.f);
          float v2 = fmaxf(acc1[ri][cf][2]*sc.z + of.z, 0.f);
          float v3 = fmaxf(acc1[ri][cf][3]*sc.w + of.w, 0.f);
          stF4(nxt, cf*16 + k, hl, 4, v0, v1, v2, v3);
        }
      }
      __syncthreads();
    }
  }

  // ---- zero agg staging region (hid0 first 8KB = NKS=8 cf0 frags) ----
  // hid0 last read was L2(6) (before c=6's barrier); c=7 uses hid1 only.
  {
    uint2 z; z.x = 0u; z.y = 0u;
    char* bz = (char*)hid0 + tid*32;
#pragma unroll
    for (int t = 0; t < 4; t++) *(uint2*)(bz + t*8) = z;
  }
  __syncthreads();

  // ---- softmax over k (width-16 xor) + aggregation -> hid0 agg tile ----
#pragma unroll
  for (int fc = 0; fc < 4; fc++) {
    int j = knnB[(size_t)(pi0 + fc) * KNN_ + k];
    const float* qp = kqvB + (size_t)(pi0 + fc)*LKV + 256;
    const float* kp = kqvB + (size_t)j*LKV;
    const float* vp = kqvB + (size_t)(pi0 + fc)*LKV + 512;
#pragma unroll
    for (int fr = 0; fr < 4; fr++) {
      int ch0 = w*64 + fr*16 + g*4;
      float q4[4], k4[4], v4[4], s4[4], res[4];
      *(float4*)q4 = *(const float4*)(qp + ch0);
      *(float4*)k4 = *(const float4*)(kp + ch0);
      *(float4*)v4 = *(const float4*)(vp + ch0);
      ldF4(s_t, fc*16 + k, ch0, 8, s4);
#pragma unroll
      for (int r = 0; r < 4; r++) {
        float a = acc2[fr][fc][r];
        float m = a;
        m = fmaxf(m, __shfl_xor(m, 1, 16)); m = fmaxf(m, __shfl_xor(m, 2, 16));
        m = fmaxf(m, __shfl_xor(m, 4, 16)); m = fmaxf(m, __shfl_xor(m, 8, 16));
        float ex = __expf(a - m);
        float se = ex;
        se += __shfl_xor(se, 1, 16); se += __shfl_xor(se, 2, 16);
        se += __shfl_xor(se, 4, 16); se += __shfl_xor(se, 8, 16);
        float watt = ex / se;
        float ve = v4[r] - q4[r] + s4[r] + k4[r];
        float cc = watt * ve;
        cc += __shfl_xor(cc, 1, 16); cc += __shfl_xor(cc, 2, 16);
        cc += __shfl_xor(cc, 4, 16); cc += __shfl_xor(cc, 8, 16);
        res[r] = cc;
      }
      if (k == 0)
        stF4(hid0, fc, ch0, 8, res[0], res[1], res[2], res[3]);
    }
  }
  __syncthreads();

  // ---- w_end stage: out = w_end @ agg + b_end + x (cols 0..3 of B-tile real) ----
  {
    f32x4 oacc[2] = {};
#pragma unroll
    for (int ks = 0; ks < 8; ks++) {
      s8v a0 = ldpk(wendpk, w*2 + 0, 8, ks, l);
      s8v a1 = ldpk(wendpk, w*2 + 1, 8, ks, l);
      s8v bF = ldF(hid0, 0, ks, 8, l);
      oacc[0] = MFMA_B16(a0, bF, oacc[0]);
      oacc[1] = MFMA_B16(a1, bF, oacc[1]);
    }
    int p = l & 15;
    if (p < 4) {
      int g4 = l >> 4;
#pragma unroll
      for (int ri = 0; ri < 2; ri++) {
#pragma unroll
        for (int r = 0; r < 4; r++) {
          int m = (w*2 + ri)*16 + g4*4 + r;
          size_t o = ((size_t)(b*128) + m)*NP + pi0 + p;
          outp[o] = oacc[ri][r] + b_endv[m] + xin[o];
        }
      }
    }
  }
}

// ---------------- launch ----------------
extern "C" void kernel_launch(void* const* d_in, const int* in_sizes, int n_in,
                              void* d_out, int out_size, void* d_ws, size_t ws_size,
                              hipStream_t stream)
{
  const float* x        = (const float*)d_in[0];
  const float* pos      = (const float*)d_in[1];
  const float* P_anchor = (const float*)d_in[3];
  const int*   map_idx  = (const int*)  d_in[4];
  const float* adist    = (const float*)d_in[5];
  const float* w_start  = (const float*)d_in[6];
  const float* b_start  = (const float*)d_in[7];
  const float* w_key    = (const float*)d_in[8];
  const float* b_key    = (const float*)d_in[9];
  const float* w_query  = (const float*)d_in[10];
  const float* b_query  = (const float*)d_in[11];
  const float* w_value  = (const float*)d_in[12];
  const float* b_value  = (const float*)d_in[13];
  const float* pw1      = (const float*)d_in[14];
  const float* pb1      = (const float*)d_in[15];
  const float* pg1      = (const float*)d_in[16];
  const float* pbt1     = (const float*)d_in[17];
  const float* pw2      = (const float*)d_in[18];
  const float* pb2      = (const float*)d_in[19];
  const float* lw1      = (const float*)d_in[20];
  const float* lw2      = (const float*)d_in[21];
  const float* lw3      = (const float*)d_in[22];
  const float* aw1      = (const float*)d_in[23];
  const float* ab1      = (const float*)d_in[24];
  const float* ag1      = (const float*)d_in[25];
  const float* abt1     = (const float*)d_in[26];
  const float* aw2      = (const float*)d_in[27];
  const float* ab2      = (const float*)d_in[28];
  const float* w_end    = (const float*)d_in[29];
  const float* b_end    = (const float*)d_in[30];

  if (ws_size < (size_t)4672384 * 4) return;   // 18.7 MB (ws proven >= 23.4 MB)

  float* ws     = (float*)d_ws;
  float* kqvT   = ws + 1048576;         // (b,2048,768) f32 interleaved K|Q|V
  u16*   aw1pk  = (u16*)(ws + 4194304);
  u16*   aw2pk  = (u16*)(ws + 4325376);
  u16*   wppk   = (u16*)(ws + 4456448);
  u16*   wstpk  = (u16*)(ws + 4472832);
  u16*   wkqvpk = (u16*)(ws + 4489216);
  u16*   wendpk = (u16*)(ws + 4587520);
  float* sa     = ws + 4603904;
  float* oa     = ws + 4604928;
  float* sp     = ws + 4605952;
  float* op_    = ws + 4606016;
  float* bkqv   = ws + 4606080;
  int*   knn_i  = (int*)(ws + 4606848);

  // merged prep + knn: blocks 0-255 knn, 256..1057 prep (821056 elements)
  prep_knn<<<1058, 1024, 0, stream>>>(pos, knn_i,
      aw1, aw2, lw3, pw2, w_start, w_key, w_query, w_value, w_end,
      b_key, b_query, b_value, ag1, ab1, abt1, pg1, pb1, pbt1,
      aw1pk, aw2pk, wppk, wstpk, wkqvpk, wendpk, sa, oa, sp, op_, bkqv);

  // kqvT = [w_key;w_query;w_value] @ (w_start @ x + b_start) + bkqv
  kqv_fused<<<dim3(32, 6, 2), 256, 0, stream>>>(
      wstpk, b_start, wkqvpk, bkqv, x, kqvT);

  // fused geometric MLPs + attention MLP + softmax + aggregation + w_end + residual
  fused_attn<<<1024, 256, 0, stream>>>(kqvT, knn_i,
      pos, map_idx, P_anchor, adist,
      lw1, lw2, pw1, sp, op_, pb2,
      aw1pk, sa, oa, aw2pk, wppk, ab2,
      wendpk, b_end, x, (float*)d_out);
}